// Round 2
// baseline (494.925 us; speedup 1.0000x reference)
//
#include <hip/hip_runtime.h>
#include <math.h>

// Problem constants
#define NN 1024      // N
#define DD 64        // D
#define TT 2048      // T
#define UDEC 0.97f
#define EPS 1e-6f

// rho/a* path chunking
#define CC 64        // chunk length along t
#define NCH 32       // TT/CC
#define NSL 16       // N-slices
#define SLW 64       // NN/NSL
// X prefix-scan chunking
#define C2 8
#define NC2 256      // TT/C2

#define NBLK 1024    // 4 blocks/CU on 256 CUs
#define NTHR 256
#define BSL 16       // distributed barrier slots (64B-padded)

// Swizzled [64][64] fp32 LDS tile: element (r,c) lives at float4-block
// r*16 + ((c>>2) ^ (r&15)), lane (c&3). Row reads AND column-of-rows float4
// reads are then bank-spread (padding can't do both for 16B-aligned rows).
__device__ __forceinline__ int swz4(int r, int c4) { return r * 16 + (c4 ^ (r & 15)); }

#define DOT4(p, q2) ((p).x*(q2).x + (p).y*(q2).y + (p).z*(q2).z + (p).w*(q2).w)

// ---- dynamic-LDS overlays (max = SmP3 ~32.3 KB) ----
struct SmP1 { float Vs[C2][DD]; };
struct SmP2 { float sc[NTHR]; };
struct SmP3 { float Xs[CC * DD]; float Vw[CC * DD]; float pw[CC + 1]; };
struct SmP4 { float ssl[4][DD + 1]; };
struct SmP5 { float Xs[CC * DD]; float Rs[DD * DD]; };
struct SmP6 { float Ve[CC][DD]; float Gt[4][CC]; float Pt[4][DD]; float pw[CC + 1]; };
struct SmP7 { float Ys[4][NN]; float L[4][DD]; float pre[4][DD + 1]; float mrow[4]; float srow[4]; };
#define SMEM_BYTES 33280

// Grid barrier, monotone cumulative targets. 16 padded counters cut arrival
// serialization 16x vs round-1's single counter. Capped spin: fail loud, no hang.
__device__ __forceinline__ void gridbar(unsigned* bar, unsigned target) {
    __syncthreads();
    if (threadIdx.x == 0) {
        __builtin_amdgcn_fence(__ATOMIC_RELEASE, "agent");
        atomicAdd(&bar[(blockIdx.x & (BSL - 1)) * 16], 1u);
        int spins = 0;
        for (;;) {
            unsigned s = 0;
#pragma unroll
            for (int i = 0; i < BSL; ++i)
                s += __hip_atomic_load(&bar[i * 16], __ATOMIC_RELAXED, __HIP_MEMORY_SCOPE_AGENT);
            if (s >= target) break;
            __builtin_amdgcn_s_sleep(2);
            if (++spins > (1 << 20)) break;
        }
        __builtin_amdgcn_fence(__ATOMIC_ACQUIRE, "agent");
    }
    __syncthreads();
}

__global__ __launch_bounds__(NTHR, 4) void fused_bdh(
    const float* __restrict__ E, const float* __restrict__ Dx,
    const float* __restrict__ Dy, const float* __restrict__ temb,
    const float* __restrict__ x0, const float* __restrict__ rho0,
    const int* __restrict__ toks,
    float* __restrict__ ys, float* __restrict__ vs,
    float* __restrict__ Xp, float* __restrict__ S, float* __restrict__ Bb,
    float* __restrict__ M, float* __restrict__ Rho, float* __restrict__ LNA,
    float* __restrict__ Gp, float* __restrict__ Pp, unsigned* __restrict__ bar)
{
    extern __shared__ __align__(16) char smem[];
    const int b = blockIdx.x, tid = threadIdx.x;

    // ---------------- P1: X chunk-scan, chunks of C2=8 tokens -------------------------
    {
        SmP1* sm = (SmP1*)smem;
        const int cs = b >> 2, qx = b & 3;
        const int n = qx * 256 + tid;
        for (int i = tid; i < C2 * DD; i += NTHR) {
            int s = i >> 6, d = i & 63;
            sm->Vs[s][d] = temb[toks[cs * C2 + s] * DD + d];
        }
        __syncthreads();
        float dxr[DD];
        const float4* dx4 = reinterpret_cast<const float4*>(Dx + n * DD);
#pragma unroll
        for (int j = 0; j < 16; ++j) {
            float4 v = dx4[j];
            dxr[4*j] = v.x; dxr[4*j+1] = v.y; dxr[4*j+2] = v.z; dxr[4*j+3] = v.w;
        }
        float run = 0.f;
        for (int s = 0; s < C2; ++s) {
            const float4* vr = reinterpret_cast<const float4*>(&sm->Vs[s][0]);
            float a0 = 0.f, a1 = 0.f, a2 = 0.f, a3 = 0.f;
#pragma unroll
            for (int j = 0; j < 16; ++j) {
                float4 v = vr[j];
                a0 += v.x * dxr[4*j];     a1 += v.y * dxr[4*j+1];
                a2 += v.z * dxr[4*j+2];   a3 += v.w * dxr[4*j+3];
            }
            run += fmaxf((a0 + a1) + (a2 + a3), 0.f);
            Xp[(cs * C2 + s) * NN + n] = run;
        }
        S[cs * NN + n] = run;
    }
    gridbar(bar, 1 * NBLK);

    // ---------------- P2: per-n block scan of 256 chunk totals -> Bb ------------------
    {
        SmP2* sm = (SmP2*)smem;
        const int n = b;                       // one n per block, 1024 blocks
        float val = S[tid * NN + n];
        sm->sc[tid] = val;
        __syncthreads();
        for (int off = 1; off < NTHR; off <<= 1) {
            float tv = (tid >= off) ? sm->sc[tid - off] : 0.f;
            __syncthreads();
            sm->sc[tid] += tv;
            __syncthreads();
        }
        Bb[tid * NN + n] = x0[n] + sm->sc[tid] - val;   // exclusive + x0
    }
    gridbar(bar, 2 * NBLK);

    // ---------------- P3: per (chunk,slice): role0 = M, role1 = Gram ------------------
    {
        SmP3* sm = (SmP3*)smem;
        const int c = b >> 5, q = (b >> 1) & 15, role = b & 1;
        if (role == 0 && tid <= CC) sm->pw[tid] = powf(UDEC, (float)tid);
        for (int i = tid; i < CC * SLW; i += NTHR) {
            int s = i >> 6, n = i & 63;
            int t = c * CC + s, gn = q * SLW + n;
            sm->Xs[swz4(s, n >> 2) * 4 + (n & 3)] = Xp[t * NN + gn] + Bb[(t >> 3) * NN + gn];
        }
        __syncthreads();
        if (role == 0) {
            for (int i = tid; i < CC * DD; i += NTHR) {
                int s = i >> 6, d = i & 63;
                sm->Vw[swz4(s, d >> 2) * 4 + (d & 3)] =
                    temb[toks[c * CC + s] * DD + d] * sm->pw[CC - s];
            }
        }
        __syncthreads();
        const float4* Xs4 = reinterpret_cast<const float4*>(sm->Xs);
        if (role == 0) {
            // M[d][n] = sum_s Vw[s][d] * Xs[s][n] : 4d x 4n per thread
            const int dg = tid >> 4, ng = tid & 15;
            float acc[16];
#pragma unroll
            for (int k = 0; k < 16; ++k) acc[k] = 0.f;
            const float4* Vw4 = reinterpret_cast<const float4*>(sm->Vw);
            for (int s = 0; s < CC; ++s) {
                float4 vw = Vw4[swz4(s, dg)];
                float4 xs = Xs4[swz4(s, ng)];
                acc[0]  += vw.x*xs.x; acc[1]  += vw.x*xs.y; acc[2]  += vw.x*xs.z; acc[3]  += vw.x*xs.w;
                acc[4]  += vw.y*xs.x; acc[5]  += vw.y*xs.y; acc[6]  += vw.y*xs.z; acc[7]  += vw.y*xs.w;
                acc[8]  += vw.z*xs.x; acc[9]  += vw.z*xs.y; acc[10] += vw.z*xs.z; acc[11] += vw.z*xs.w;
                acc[12] += vw.w*xs.x; acc[13] += vw.w*xs.y; acc[14] += vw.w*xs.z; acc[15] += vw.w*xs.w;
            }
#pragma unroll
            for (int a = 0; a < 4; ++a)
                *reinterpret_cast<float4*>(&M[(c * DD + dg * 4 + a) * NN + q * SLW + ng * 4]) =
                    make_float4(acc[a*4], acc[a*4+1], acc[a*4+2], acc[a*4+3]);
        } else {
            // G[t][s] = sum_n Xs[t][n]*Xs[s][n] : 4t x 4s per thread, n4-blocked
            const int tg = tid >> 4, sg = tid & 15;
            float acc[16];
#pragma unroll
            for (int k = 0; k < 16; ++k) acc[k] = 0.f;
            for (int n4 = 0; n4 < 16; ++n4) {
                float4 xa[4], xb[4];
#pragma unroll
                for (int a = 0; a < 4; ++a) { int r = tg * 4 + a; xa[a] = Xs4[swz4(r, n4)]; }
#pragma unroll
                for (int e = 0; e < 4; ++e) { int r = sg * 4 + e; xb[e] = Xs4[swz4(r, n4)]; }
#pragma unroll
                for (int a = 0; a < 4; ++a)
#pragma unroll
                    for (int e = 0; e < 4; ++e) acc[a*4+e] += DOT4(xa[a], xb[e]);
            }
            float* base = Gp + ((size_t)(c * NSL + q) * CC) * CC;
#pragma unroll
            for (int a = 0; a < 4; ++a)
                *reinterpret_cast<float4*>(base + (tg * 4 + a) * CC + sg * 4) =
                    make_float4(acc[a*4], acc[a*4+1], acc[a*4+2], acc[a*4+3]);
        }
    }
    gridbar(bar, 3 * NBLK);

    // ---------------- P4: segmented chunk scan of rho (4 t-segments per element) ------
    {
        SmP4* sm = (SmP4*)smem;
        const int e_l = tid & 63, seg = tid >> 6;        // seg handles 8 chunks
        const int el = b * 64 + e_l;                     // 1024*64 = DD*NN
        const float uc = powf(UDEC, (float)CC);
        const float uc8 = powf(uc, 8.0f);
        float mreg[8];
#pragma unroll
        for (int j = 0; j < 8; ++j) mreg[j] = M[(size_t)(seg * 8 + j) * (DD * NN) + el];
        float ss = 0.f;
#pragma unroll
        for (int j = 0; j < 8; ++j) ss = fmaf(ss, uc, mreg[j]);
        sm->ssl[seg][e_l] = ss;
        __syncthreads();
        float st = rho0[el];
        for (int r = 0; r < seg; ++r) st = fmaf(st, uc8, sm->ssl[r][e_l]);
        float acc = st;
#pragma unroll
        for (int j = 0; j < 8; ++j) {
            Rho[(size_t)(seg * 8 + j) * (DD * NN) + el] = acc;
            acc = fmaf(acc, uc, mreg[j]);
        }
    }
    gridbar(bar, 4 * NBLK);

    // ---------------- P5: Pp[t][d] = sum_n Xs[t][n]*Rho[d][n] per (chunk,slice) -------
    if (b < NCH * NSL) {                                 // 512 blocks
        SmP5* sm = (SmP5*)smem;
        const int c = b >> 4, q = b & 15;
        for (int i = tid; i < CC * SLW; i += NTHR) {
            int s = i >> 6, n = i & 63;
            int t = c * CC + s, gn = q * SLW + n;
            sm->Xs[swz4(s, n >> 2) * 4 + (n & 3)] = Xp[t * NN + gn] + Bb[(t >> 3) * NN + gn];
            sm->Rs[swz4(s, n >> 2) * 4 + (n & 3)] = Rho[(size_t)(c * DD + s) * NN + gn]; // DD==CC rows
        }
        __syncthreads();
        const float4* Xs4 = reinterpret_cast<const float4*>(sm->Xs);
        const float4* Rs4 = reinterpret_cast<const float4*>(sm->Rs);
        const int tg = tid >> 4, dg = tid & 15;
        float acc[16];
#pragma unroll
        for (int k = 0; k < 16; ++k) acc[k] = 0.f;
        for (int n4 = 0; n4 < 16; ++n4) {
            float4 xa[4], rv[4];
#pragma unroll
            for (int a = 0; a < 4; ++a) { int r = tg * 4 + a; xa[a] = Xs4[swz4(r, n4)]; }
#pragma unroll
            for (int e = 0; e < 4; ++e) { int r = dg * 4 + e; rv[e] = Rs4[swz4(r, n4)]; }
#pragma unroll
            for (int a = 0; a < 4; ++a)
#pragma unroll
                for (int e = 0; e < 4; ++e) acc[a*4+e] += DOT4(xa[a], rv[e]);
        }
        float* base = Pp + ((size_t)(c * NSL + q) * CC) * DD;
#pragma unroll
        for (int a = 0; a < 4; ++a)
            *reinterpret_cast<float4*>(base + (tg * 4 + a) * DD + dg * 4) =
                make_float4(acc[a*4], acc[a*4+1], acc[a*4+2], acc[a*4+3]);
    }
    gridbar(bar, 5 * NBLK);

    // ---------------- P6: a* assembly + rowwise LN (t-striped, 16 blocks/chunk) -------
    if (b < NCH * 16) {                                  // 512 blocks
        SmP6* sm = (SmP6*)smem;
        const int c = b >> 4, sub = b & 15;              // t = sub + 16k, k<4
        if (tid <= CC) sm->pw[tid] = powf(UDEC, (float)tid);
        for (int i = tid; i < CC * DD; i += NTHR) {
            int s = i >> 6, d = i & 63;
            sm->Ve[s][d] = temb[toks[c * CC + s] * DD + d];
        }
        {
            int k = tid >> 6, s = tid & 63;
            int t = sub + 16 * k;
            float ag = 0.f, ap = 0.f;
#pragma unroll
            for (int q = 0; q < NSL; ++q) {
                ag += Gp[((size_t)(c * NSL + q) * CC + t) * CC + s];
                ap += Pp[((size_t)(c * NSL + q) * CC + t) * DD + s];
            }
            sm->Gt[k][s] = ag; sm->Pt[k][s] = ap;
        }
        __syncthreads();
        const int tk = tid >> 6, d0 = tid & 63;          // one wave per t-row
        const int t = sub + 16 * tk;
        float a = sm->pw[t] * sm->Pt[tk][d0];
        for (int s = 0; s < t; ++s)
            a = fmaf(sm->pw[t - s] * sm->Gt[tk][s], sm->Ve[s][d0], a);
        float sum = a;
#pragma unroll
        for (int m = 1; m < 64; m <<= 1) sum += __shfl_xor(sum, m, 64);
        float mean = sum * (1.f / DD);
        float z = a - mean;
        float vsum = z * z;
#pragma unroll
        for (int m = 1; m < 64; m <<= 1) vsum += __shfl_xor(vsum, m, 64);
        float inv = 1.f / (sqrtf(vsum * (1.f / (DD - 1))) + EPS);
        LNA[(c * CC + t) * DD + d0] = z * inv;
    }
    gridbar(bar, 6 * NBLK);

    // ---------------- P7: y = relu(Dy@LNA)*relu(x), then v = LN(E@y), fused -----------
    if (b < TT / 4) {                                    // 512 blocks, 4 tokens each
        SmP7* sm = (SmP7*)smem;
        const int tt = b;
        sm->L[tid >> 6][tid & 63] = LNA[tt * 4 * DD + tid];
        __syncthreads();
        for (int nq = 0; nq < 4; ++nq) {
            const int n = nq * 256 + tid;
            float dyr[DD];
            const float4* dy4 = reinterpret_cast<const float4*>(Dy + n * DD);
#pragma unroll
            for (int j = 0; j < 16; ++j) {
                float4 v = dy4[j];
                dyr[4*j] = v.x; dyr[4*j+1] = v.y; dyr[4*j+2] = v.z; dyr[4*j+3] = v.w;
            }
#pragma unroll
            for (int k = 0; k < 4; ++k) {
                const float4* lr = reinterpret_cast<const float4*>(&sm->L[k][0]);
                float a0 = 0.f, a1 = 0.f, a2 = 0.f, a3 = 0.f;
#pragma unroll
                for (int j = 0; j < 16; ++j) {
                    float4 v = lr[j];
                    a0 += v.x * dyr[4*j];   a1 += v.y * dyr[4*j+1];
                    a2 += v.z * dyr[4*j+2]; a3 += v.w * dyr[4*j+3];
                }
                float yc = (a0 + a1) + (a2 + a3);
                int tg = tt * 4 + k;
                float xv = Xp[tg * NN + n] + Bb[(tg >> 3) * NN + n];
                float yv = fmaxf(yc, 0.f) * fmaxf(xv, 0.f);
                ys[tg * NN + n] = yv;
                sm->Ys[k][n] = yv;
            }
        }
        __syncthreads();
        {
            const int k = tid >> 6, d = tid & 63;
            const float4* e4 = reinterpret_cast<const float4*>(E + d * NN);
            const float4* y4 = reinterpret_cast<const float4*>(&sm->Ys[k][0]);
            float a0 = 0.f, a1 = 0.f, a2 = 0.f, a3 = 0.f;
            for (int j = 0; j < NN / 4; ++j) {
                float4 ev = e4[j], yv = y4[j];
                a0 += ev.x * yv.x; a1 += ev.y * yv.y; a2 += ev.z * yv.z; a3 += ev.w * yv.w;
            }
            sm->pre[k][d] = (a0 + a1) + (a2 + a3);
        }
        __syncthreads();
        if (tid < 4) {
            float m = 0.f;
#pragma unroll
            for (int dd2 = 0; dd2 < DD; ++dd2) m += sm->pre[tid][dd2];
            m *= (1.f / DD);
            float v = 0.f;
#pragma unroll
            for (int dd2 = 0; dd2 < DD; ++dd2) { float z = sm->pre[tid][dd2] - m; v += z * z; }
            sm->mrow[tid] = m;
            sm->srow[tid] = 1.f / (sqrtf(v * (1.f / (DD - 1))) + EPS);
        }
        __syncthreads();
        {
            int k = tid >> 6, d = tid & 63;
            vs[(tt * 4 + k) * DD + d] = (sm->pre[k][d] - sm->mrow[k]) * sm->srow[k];
        }
    }
}

// ---------------------------------------------------------------------------
extern "C" void kernel_launch(void* const* d_in, const int* in_sizes, int n_in,
                              void* d_out, int out_size, void* d_ws, size_t ws_size,
                              hipStream_t stream) {
    (void)in_sizes; (void)n_in; (void)out_size; (void)ws_size;
    const float* E    = (const float*)d_in[0];   // [D,N]
    const float* Dx   = (const float*)d_in[1];   // [N,D]
    const float* Dy   = (const float*)d_in[2];   // [N,D]
    const float* temb = (const float*)d_in[3];   // [V,D]
    const float* x0   = (const float*)d_in[4];   // [N]
    const float* rho0 = (const float*)d_in[5];   // [D,N]
    const int*   toks = (const int*)d_in[6];     // [T]

    float* ys = (float*)d_out;                   // [T,N]
    float* vs = ys + (size_t)TT * NN;            // [T,D]

    // Workspace ~34.5 MiB (same as round-1 proven footprint; Pp aliases M:
    // M dead after P4/barrier-4, Pp first written in P5).
    float* w   = (float*)d_ws;
    float* Xp  = w;                                  // TT*NN       (8 MB)
    float* S   = Xp  + (size_t)TT * NN;              // NC2*NN      (1 MB)
    float* Bb  = S   + (size_t)NC2 * NN;             // NC2*NN      (1 MB)
    float* M   = Bb  + (size_t)NC2 * NN;             // NCH*DD*NN   (8 MB)
    float* Rho = M   + (size_t)NCH * DD * NN;        // NCH*DD*NN   (8 MB)
    float* LNA = Rho + (size_t)NCH * DD * NN;        // TT*DD       (0.5 MB)
    float* Gp  = LNA + (size_t)TT * DD;              // NCH*NSL*CC*CC (8 MB)
    float* Pp  = M;                                  // alias (exactly M's size)
    unsigned* bar = (unsigned*)(Gp + (size_t)NCH * NSL * CC * CC);

    hipMemsetAsync(bar, 0, BSL * 16 * sizeof(unsigned), stream);
    hipLaunchKernelGGL(fused_bdh, dim3(NBLK), dim3(NTHR), SMEM_BYTES, stream,
                       E, Dx, Dy, temb, x0, rho0, toks, ys, vs,
                       Xp, S, Bb, M, Rho, LNA, Gp, Pp, bar);
}

// Round 3
// 418.534 us; speedup vs baseline: 1.1825x; 1.1825x over previous
//
#include <hip/hip_runtime.h>
#include <math.h>

// Problem constants
#define NN 1024      // N
#define DD 64        // D
#define TT 2048      // T
#define UDEC 0.97f
#define EPS 1e-6f

// rho/a* path chunking
#define CC 64        // chunk length along t
#define NCH 32       // TT/CC
#define NSL 16       // N-slices
#define SLW 64       // NN/NSL
// X prefix-scan chunking
#define C2 8
#define NC2 256      // TT/C2

#define NBLK 1024    // 4 blocks/CU on 256 CUs
#define NTHR 256
#define BSL 16       // arrival slots (64B-padded)
#define GSL 8        // replicated go-epoch lines

// Swizzled [R][64] fp32 LDS tile: element (r,c) at float4-block r*16+((c>>2)^(r&15)).
__device__ __forceinline__ int swz4(int r, int c4) { return r * 16 + (c4 ^ (r & 15)); }

#define DOT4(p, q2) ((p).x*(q2).x + (p).y*(q2).y + (p).z*(q2).z + (p).w*(q2).w)

// ---- dynamic-LDS overlays (max = SmP3 ~32.3 KB) ----
struct SmP1 { float Vs[C2][DD]; };
struct SmP2 { float ssl[8][33]; };
struct SmP3 { float Xs[CC * DD]; float Vw[CC * DD]; float pw[CC + 1]; };
struct SmP4 { float ssl[4][DD + 1]; };
struct SmP5 { float Xs[32 * DD]; float Rs[DD * DD]; };
struct SmP67 {
    float VeYs[4 * NN];                 // Ve[s][d]=VeYs[s*64+d] then Ys[k][n]=VeYs[k*1024+n]
    float Gt[4][CC]; float Pt[4][DD]; float pw[CC + 1];
    float L[4][DD]; float pre[4][DD + 1]; float mrow[4]; float srow[4];
};
#define SMEM_BYTES 33280

// Two-level epoch grid barrier.
// Arrive: +1 on one of 16 padded slot lines (<=64 serialized adds per line).
// Block 0 aggregates the 16 slots, then publishes the phase number to 8
// replicated go-lines. All other leaders poll ONE go-line with long sleep:
// poll traffic ~0.15 G loads/s total (round-2's 16-line tight spin was ~20 G/s
// of agent-scope LLC traffic -- the theory for the 434us regression).
__device__ __forceinline__ void gridbar(unsigned* slots, unsigned* go, unsigned phase) {
    __syncthreads();
    if (threadIdx.x == 0) {
        __builtin_amdgcn_fence(__ATOMIC_RELEASE, "agent");
        atomicAdd(&slots[(blockIdx.x & (BSL - 1)) * 16], 1u);
        if (blockIdx.x == 0) {
            int spins = 0;
            for (;;) {
                unsigned s = 0;
#pragma unroll
                for (int i = 0; i < BSL; ++i)
                    s += __hip_atomic_load(&slots[i * 16], __ATOMIC_RELAXED, __HIP_MEMORY_SCOPE_AGENT);
                if (s >= phase * NBLK) break;
                __builtin_amdgcn_s_sleep(4);
                if (++spins > (1 << 17)) break;          // safety hatch
            }
            __builtin_amdgcn_fence(__ATOMIC_ACQ_REL, "agent");
#pragma unroll
            for (int i = 0; i < GSL; ++i)
                __hip_atomic_store(&go[i * 16], phase, __ATOMIC_RELAXED, __HIP_MEMORY_SCOPE_AGENT);
        } else {
            unsigned* myg = &go[(blockIdx.x & (GSL - 1)) * 16];
            int spins = 0;
            while (__hip_atomic_load(myg, __ATOMIC_RELAXED, __HIP_MEMORY_SCOPE_AGENT) < phase) {
                __builtin_amdgcn_s_sleep(32);            // ~0.85us poll period
                if (++spins > (1 << 15)) break;          // safety hatch (~50ms)
            }
        }
        __builtin_amdgcn_fence(__ATOMIC_ACQUIRE, "agent");
    }
    __syncthreads();
}

__global__ __launch_bounds__(NTHR, 4) void fused_bdh(
    const float* __restrict__ E, const float* __restrict__ Dx,
    const float* __restrict__ Dy, const float* __restrict__ temb,
    const float* __restrict__ x0, const float* __restrict__ rho0,
    const int* __restrict__ toks,
    float* __restrict__ ys, float* __restrict__ vs,
    float* __restrict__ Xp, float* __restrict__ S, float* __restrict__ Bb,
    float* __restrict__ M, float* __restrict__ Rho,
    float* __restrict__ Gp, float* __restrict__ Pp,
    unsigned* __restrict__ slots, unsigned* __restrict__ go)
{
    extern __shared__ __align__(16) char smem[];
    const int b = blockIdx.x, tid = threadIdx.x;

    // ---------------- P1: X chunk-scan, chunks of C2=8 tokens -------------------------
    {
        SmP1* sm = (SmP1*)smem;
        const int cs = b >> 2, qx = b & 3;
        const int n = qx * 256 + tid;
        for (int i = tid; i < C2 * DD; i += NTHR) {
            int s = i >> 6, d = i & 63;
            sm->Vs[s][d] = temb[toks[cs * C2 + s] * DD + d];
        }
        __syncthreads();
        float dxr[DD];
        const float4* dx4 = reinterpret_cast<const float4*>(Dx + n * DD);
#pragma unroll
        for (int j = 0; j < 16; ++j) {
            float4 v = dx4[j];
            dxr[4*j] = v.x; dxr[4*j+1] = v.y; dxr[4*j+2] = v.z; dxr[4*j+3] = v.w;
        }
        float run = 0.f;
        for (int s = 0; s < C2; ++s) {
            const float4* vr = reinterpret_cast<const float4*>(&sm->Vs[s][0]);
            float a0 = 0.f, a1 = 0.f, a2 = 0.f, a3 = 0.f;
#pragma unroll
            for (int j = 0; j < 16; ++j) {
                float4 v = vr[j];
                a0 += v.x * dxr[4*j];     a1 += v.y * dxr[4*j+1];
                a2 += v.z * dxr[4*j+2];   a3 += v.w * dxr[4*j+3];
            }
            run += fmaxf((a0 + a1) + (a2 + a3), 0.f);
            Xp[(cs * C2 + s) * NN + n] = run;
        }
        S[cs * NN + n] = run;
    }
    gridbar(slots, go, 1);

    // ---------------- P2: segmented scan of 256 chunk totals -> Bb (32 blocks) --------
    if (b < 32) {
        SmP2* sm = (SmP2*)smem;
        const int n_l = tid & 31, seg = tid >> 5;        // 8 segs x 32 chunks
        const int n = b * 32 + n_l;
        float m[32];
#pragma unroll
        for (int j = 0; j < 32; ++j) m[j] = S[(seg * 32 + j) * NN + n];
        float tot = 0.f;
#pragma unroll
        for (int j = 0; j < 32; ++j) tot += m[j];
        sm->ssl[seg][n_l] = tot;
        __syncthreads();
        float acc = x0[n];
        for (int r = 0; r < seg; ++r) acc += sm->ssl[r][n_l];
#pragma unroll
        for (int j = 0; j < 32; ++j) {
            Bb[(seg * 32 + j) * NN + n] = acc;           // exclusive prefix + x0
            acc += m[j];
        }
    }
    gridbar(slots, go, 2);

    // ---------------- P3: per (chunk,slice): role0 = M, role1 = Gram ------------------
    {
        SmP3* sm = (SmP3*)smem;
        const int c = b >> 5, q = (b >> 1) & 15, role = b & 1;
        if (role == 0 && tid <= CC) sm->pw[tid] = powf(UDEC, (float)tid);
        for (int i = tid; i < CC * SLW; i += NTHR) {
            int s = i >> 6, n = i & 63;
            int t = c * CC + s, gn = q * SLW + n;
            sm->Xs[swz4(s, n >> 2) * 4 + (n & 3)] = Xp[t * NN + gn] + Bb[(t >> 3) * NN + gn];
        }
        __syncthreads();
        if (role == 0) {
            for (int i = tid; i < CC * DD; i += NTHR) {
                int s = i >> 6, d = i & 63;
                sm->Vw[swz4(s, d >> 2) * 4 + (d & 3)] =
                    temb[toks[c * CC + s] * DD + d] * sm->pw[CC - s];
            }
        }
        __syncthreads();
        const float4* Xs4 = reinterpret_cast<const float4*>(sm->Xs);
        if (role == 0) {
            const int dg = tid >> 4, ng = tid & 15;
            float acc[16];
#pragma unroll
            for (int k = 0; k < 16; ++k) acc[k] = 0.f;
            const float4* Vw4 = reinterpret_cast<const float4*>(sm->Vw);
            for (int s = 0; s < CC; ++s) {
                float4 vw = Vw4[swz4(s, dg)];
                float4 xs = Xs4[swz4(s, ng)];
                acc[0]  += vw.x*xs.x; acc[1]  += vw.x*xs.y; acc[2]  += vw.x*xs.z; acc[3]  += vw.x*xs.w;
                acc[4]  += vw.y*xs.x; acc[5]  += vw.y*xs.y; acc[6]  += vw.y*xs.z; acc[7]  += vw.y*xs.w;
                acc[8]  += vw.z*xs.x; acc[9]  += vw.z*xs.y; acc[10] += vw.z*xs.z; acc[11] += vw.z*xs.w;
                acc[12] += vw.w*xs.x; acc[13] += vw.w*xs.y; acc[14] += vw.w*xs.z; acc[15] += vw.w*xs.w;
            }
#pragma unroll
            for (int a = 0; a < 4; ++a)
                *reinterpret_cast<float4*>(&M[(c * DD + dg * 4 + a) * NN + q * SLW + ng * 4]) =
                    make_float4(acc[a*4], acc[a*4+1], acc[a*4+2], acc[a*4+3]);
        } else {
            const int tg = tid >> 4, sg = tid & 15;
            float acc[16];
#pragma unroll
            for (int k = 0; k < 16; ++k) acc[k] = 0.f;
            for (int n4 = 0; n4 < 16; ++n4) {
                float4 xa[4], xb[4];
#pragma unroll
                for (int a = 0; a < 4; ++a) xa[a] = Xs4[swz4(tg * 4 + a, n4)];
#pragma unroll
                for (int e = 0; e < 4; ++e) xb[e] = Xs4[swz4(sg * 4 + e, n4)];
#pragma unroll
                for (int a = 0; a < 4; ++a)
#pragma unroll
                    for (int e = 0; e < 4; ++e) acc[a*4+e] += DOT4(xa[a], xb[e]);
            }
            float* base = Gp + ((size_t)(c * NSL + q) * CC) * CC;
#pragma unroll
            for (int a = 0; a < 4; ++a)
                *reinterpret_cast<float4*>(base + (tg * 4 + a) * CC + sg * 4) =
                    make_float4(acc[a*4], acc[a*4+1], acc[a*4+2], acc[a*4+3]);
        }
    }
    gridbar(slots, go, 3);

    // ---------------- P4: segmented chunk scan of rho ---------------------------------
    {
        SmP4* sm = (SmP4*)smem;
        const int e_l = tid & 63, seg = tid >> 6;        // seg handles 8 chunks
        const int el = b * 64 + e_l;                     // 1024*64 = DD*NN
        const float uc = powf(UDEC, (float)CC);
        const float uc8 = powf(uc, 8.0f);
        float mreg[8];
#pragma unroll
        for (int j = 0; j < 8; ++j) mreg[j] = M[(size_t)(seg * 8 + j) * (DD * NN) + el];
        float ss = 0.f;
#pragma unroll
        for (int j = 0; j < 8; ++j) ss = fmaf(ss, uc, mreg[j]);
        sm->ssl[seg][e_l] = ss;
        __syncthreads();
        float st = rho0[el];
        for (int r = 0; r < seg; ++r) st = fmaf(st, uc8, sm->ssl[r][e_l]);
        float acc = st;
#pragma unroll
        for (int j = 0; j < 8; ++j) {
            Rho[(size_t)(seg * 8 + j) * (DD * NN) + el] = acc;
            acc = fmaf(acc, uc, mreg[j]);
        }
    }
    gridbar(slots, go, 4);

    // ---------------- P5: Pp[t][d] = sum_n X[t][n]*Rho[d][n], (c,q,t-half) ------------
    {
        SmP5* sm = (SmP5*)smem;
        const int c = b >> 5, q = (b >> 1) & 15, h = b & 1;
        for (int i = tid; i < 32 * SLW; i += NTHR) {
            int s = i >> 6, n = i & 63;                  // s: 32 t-rows of this half
            int t = c * CC + h * 32 + s, gn = q * SLW + n;
            sm->Xs[swz4(s, n >> 2) * 4 + (n & 3)] = Xp[t * NN + gn] + Bb[(t >> 3) * NN + gn];
        }
        for (int i = tid; i < DD * SLW; i += NTHR) {
            int s = i >> 6, n = i & 63;                  // s: all 64 d-rows
            int gn = q * SLW + n;
            sm->Rs[swz4(s, n >> 2) * 4 + (n & 3)] = Rho[(size_t)(c * DD + s) * NN + gn];
        }
        __syncthreads();
        const float4* Xs4 = reinterpret_cast<const float4*>(sm->Xs);
        const float4* Rs4 = reinterpret_cast<const float4*>(sm->Rs);
        const int ti = tid >> 4, dg = tid & 15;          // 2 t x 4 d per thread
        float acc[8];
#pragma unroll
        for (int k = 0; k < 8; ++k) acc[k] = 0.f;
        for (int n4 = 0; n4 < 16; ++n4) {
            float4 xa[2], rv[4];
#pragma unroll
            for (int a = 0; a < 2; ++a) xa[a] = Xs4[swz4(ti * 2 + a, n4)];
#pragma unroll
            for (int e = 0; e < 4; ++e) rv[e] = Rs4[swz4(dg * 4 + e, n4)];
#pragma unroll
            for (int a = 0; a < 2; ++a)
#pragma unroll
                for (int e = 0; e < 4; ++e) acc[a*4+e] += DOT4(xa[a], rv[e]);
        }
#pragma unroll
        for (int a = 0; a < 2; ++a) {
            int trow = h * 32 + ti * 2 + a;
            *reinterpret_cast<float4*>(
                Pp + (((size_t)(c * NSL + q) * CC) + trow) * DD + dg * 4) =
                make_float4(acc[a*4], acc[a*4+1], acc[a*4+2], acc[a*4+3]);
        }
    }
    gridbar(slots, go, 5);

    // ---------------- P6+7 fused: a* + LN + y + v (512 blocks, 4 tokens each) ---------
    if (b < NCH * 16) {
        SmP67* sm = (SmP67*)smem;
        const int c = b >> 4, sub = b & 15;              // tokens t = sub + 16k, k<4
        if (tid <= CC) sm->pw[tid] = powf(UDEC, (float)tid);
        for (int i = tid; i < CC * DD; i += NTHR) {
            int s = i >> 6, d = i & 63;
            sm->VeYs[s * 64 + d] = temb[toks[c * CC + s] * DD + d];   // Ve[s][d]
        }
        {
            int k = tid >> 6, s = tid & 63;
            int t = sub + 16 * k;
            float ag = 0.f, ap = 0.f;
#pragma unroll
            for (int q = 0; q < NSL; ++q) {
                ag += Gp[((size_t)(c * NSL + q) * CC + t) * CC + s];
                ap += Pp[((size_t)(c * NSL + q) * CC + t) * DD + s];
            }
            sm->Gt[k][s] = ag; sm->Pt[k][s] = ap;
        }
        __syncthreads();
        {   // a* + LN, one wave per t-row
            const int tk = tid >> 6, d0 = tid & 63;
            const int t = sub + 16 * tk;
            float a = sm->pw[t] * sm->Pt[tk][d0];
            for (int s = 0; s < t; ++s)
                a = fmaf(sm->pw[t - s] * sm->Gt[tk][s], sm->VeYs[s * 64 + d0], a);
            float sum = a;
#pragma unroll
            for (int mm = 1; mm < 64; mm <<= 1) sum += __shfl_xor(sum, mm, 64);
            float mean = sum * (1.f / DD);
            float z = a - mean;
            float vv = z * z;
#pragma unroll
            for (int mm = 1; mm < 64; mm <<= 1) vv += __shfl_xor(vv, mm, 64);
            float inv = 1.f / (sqrtf(vv * (1.f / (DD - 1))) + EPS);
            sm->L[tk][d0] = z * inv;
        }
        __syncthreads();                                  // L ready; Ve dead -> reuse as Ys
        for (int nq = 0; nq < 4; ++nq) {
            const int n = nq * 256 + tid;
            float dyr[DD];
            const float4* dy4 = reinterpret_cast<const float4*>(Dy + n * DD);
#pragma unroll
            for (int j = 0; j < 16; ++j) {
                float4 v = dy4[j];
                dyr[4*j] = v.x; dyr[4*j+1] = v.y; dyr[4*j+2] = v.z; dyr[4*j+3] = v.w;
            }
#pragma unroll
            for (int k = 0; k < 4; ++k) {
                const float4* lr = reinterpret_cast<const float4*>(&sm->L[k][0]);
                float a0 = 0.f, a1 = 0.f, a2 = 0.f, a3 = 0.f;
#pragma unroll
                for (int j = 0; j < 16; ++j) {
                    float4 v = lr[j];
                    a0 += v.x * dyr[4*j];   a1 += v.y * dyr[4*j+1];
                    a2 += v.z * dyr[4*j+2]; a3 += v.w * dyr[4*j+3];
                }
                float yc = (a0 + a1) + (a2 + a3);
                int tg = c * CC + sub + 16 * k;
                float xv = Xp[tg * NN + n] + Bb[(tg >> 3) * NN + n];
                float yv = fmaxf(yc, 0.f) * fmaxf(xv, 0.f);
                ys[tg * NN + n] = yv;
                sm->VeYs[k * NN + n] = yv;                // Ys[k][n]
            }
        }
        __syncthreads();
        {   // v = LN(E @ y)
            const int k = tid >> 6, d = tid & 63;
            const float4* e4 = reinterpret_cast<const float4*>(E + d * NN);
            const float4* y4 = reinterpret_cast<const float4*>(&sm->VeYs[k * NN]);
            float a0 = 0.f, a1 = 0.f, a2 = 0.f, a3 = 0.f;
            for (int j = 0; j < NN / 4; ++j) {
                float4 ev = e4[j], yv = y4[j];
                a0 += ev.x * yv.x; a1 += ev.y * yv.y; a2 += ev.z * yv.z; a3 += ev.w * yv.w;
            }
            sm->pre[k][d] = (a0 + a1) + (a2 + a3);
        }
        __syncthreads();
        if (tid < 4) {
            float m = 0.f;
#pragma unroll
            for (int dd2 = 0; dd2 < DD; ++dd2) m += sm->pre[tid][dd2];
            m *= (1.f / DD);
            float v = 0.f;
#pragma unroll
            for (int dd2 = 0; dd2 < DD; ++dd2) { float z = sm->pre[tid][dd2] - m; v += z * z; }
            sm->mrow[tid] = m;
            sm->srow[tid] = 1.f / (sqrtf(v * (1.f / (DD - 1))) + EPS);
        }
        __syncthreads();
        {
            int k = tid >> 6, d = tid & 63;
            vs[(c * CC + sub + 16 * k) * DD + d] = (sm->pre[k][d] - sm->mrow[k]) * sm->srow[k];
        }
    }
}

// ---------------------------------------------------------------------------
extern "C" void kernel_launch(void* const* d_in, const int* in_sizes, int n_in,
                              void* d_out, int out_size, void* d_ws, size_t ws_size,
                              hipStream_t stream) {
    (void)in_sizes; (void)n_in; (void)out_size; (void)ws_size;
    const float* E    = (const float*)d_in[0];   // [D,N]
    const float* Dx   = (const float*)d_in[1];   // [N,D]
    const float* Dy   = (const float*)d_in[2];   // [N,D]
    const float* temb = (const float*)d_in[3];   // [V,D]
    const float* x0   = (const float*)d_in[4];   // [N]
    const float* rho0 = (const float*)d_in[5];   // [D,N]
    const int*   toks = (const int*)d_in[6];     // [T]

    float* ys = (float*)d_out;                   // [T,N]
    float* vs = ys + (size_t)TT * NN;            // [T,D]

    // Workspace ~34 MiB. Pp aliases M (M dead after P4; Pp written in P5).
    float* w   = (float*)d_ws;
    float* Xp  = w;                                  // TT*NN       (8 MB)
    float* S   = Xp  + (size_t)TT * NN;              // NC2*NN      (1 MB)
    float* Bb  = S   + (size_t)NC2 * NN;             // NC2*NN      (1 MB)
    float* M   = Bb  + (size_t)NC2 * NN;             // NCH*DD*NN   (8 MB)
    float* Rho = M   + (size_t)NCH * DD * NN;        // NCH*DD*NN   (8 MB)
    float* Gp  = Rho + (size_t)NCH * DD * NN;        // NCH*NSL*CC*CC (8 MB)
    float* Pp  = M;                                  // alias
    unsigned* slots = (unsigned*)(Gp + (size_t)NCH * NSL * CC * CC);
    unsigned* go    = slots + BSL * 16;

    hipMemsetAsync(slots, 0, (BSL + GSL) * 16 * sizeof(unsigned), stream);
    hipLaunchKernelGGL(fused_bdh, dim3(NBLK), dim3(NTHR), SMEM_BYTES, stream,
                       E, Dx, Dy, temb, x0, rho0, toks, ys, vs,
                       Xp, S, Bb, M, Rho, Gp, Pp, slots, go);
}

// Round 4
// 232.359 us; speedup vs baseline: 2.1300x; 1.8012x over previous
//
#include <hip/hip_runtime.h>
#include <math.h>

// Problem constants
#define NN 1024      // N
#define DD 64        // D
#define TT 2048      // T
#define UDEC 0.97f
#define EPS 1e-6f

// rho/a* path chunking
#define CC 64        // chunk length along t
#define NCH 32       // TT/CC
#define NSL 16       // N-slices
#define SLW 64       // NN/NSL
// X prefix-scan chunking
#define C2 8
#define NC2 256      // TT/C2

#define NTHR 256

// Swizzled [R][64] fp32 LDS tile: element (r,c) at float4-block r*16+((c>>2)^(r&15)).
__device__ __forceinline__ int swz4(int r, int c4) { return r * 16 + (c4 ^ (r & 15)); }

#define DOT4(p, q2) ((p).x*(q2).x + (p).y*(q2).y + (p).z*(q2).z + (p).w*(q2).w)

// ---------------------------------------------------------------------------
// K1: X chunk-scan, chunks of C2=8 tokens. 1024 blocks.
__global__ __launch_bounds__(NTHR) void k_xscan(
    const float* __restrict__ Dx, const float* __restrict__ temb,
    const int* __restrict__ toks, float* __restrict__ Xp, float* __restrict__ S)
{
    __shared__ float Vs[C2][DD];
    const int b = blockIdx.x, tid = threadIdx.x;
    const int cs = b >> 2, qx = b & 3;
    const int n = qx * 256 + tid;
    for (int i = tid; i < C2 * DD; i += NTHR) {
        int s = i >> 6, d = i & 63;
        Vs[s][d] = temb[toks[cs * C2 + s] * DD + d];
    }
    __syncthreads();
    float dxr[DD];
    const float4* dx4 = reinterpret_cast<const float4*>(Dx + n * DD);
#pragma unroll
    for (int j = 0; j < 16; ++j) {
        float4 v = dx4[j];
        dxr[4*j] = v.x; dxr[4*j+1] = v.y; dxr[4*j+2] = v.z; dxr[4*j+3] = v.w;
    }
    float run = 0.f;
    for (int s = 0; s < C2; ++s) {
        const float4* vr = reinterpret_cast<const float4*>(&Vs[s][0]);
        float a0 = 0.f, a1 = 0.f, a2 = 0.f, a3 = 0.f;
#pragma unroll
        for (int j = 0; j < 16; ++j) {
            float4 v = vr[j];
            a0 += v.x * dxr[4*j];     a1 += v.y * dxr[4*j+1];
            a2 += v.z * dxr[4*j+2];   a3 += v.w * dxr[4*j+3];
        }
        run += fmaxf((a0 + a1) + (a2 + a3), 0.f);
        Xp[(cs * C2 + s) * NN + n] = run;
    }
    S[cs * NN + n] = run;
}

// ---------------------------------------------------------------------------
// K2: segmented scan of 256 chunk totals -> exclusive base Bb. 32 blocks.
__global__ __launch_bounds__(NTHR) void k_base(
    const float* __restrict__ S, const float* __restrict__ x0, float* __restrict__ Bb)
{
    __shared__ float ssl[8][33];
    const int b = blockIdx.x, tid = threadIdx.x;
    const int n_l = tid & 31, seg = tid >> 5;            // 8 segs x 32 chunks
    const int n = b * 32 + n_l;
    float m[32];
#pragma unroll
    for (int j = 0; j < 32; ++j) m[j] = S[(seg * 32 + j) * NN + n];
    float tot = 0.f;
#pragma unroll
    for (int j = 0; j < 32; ++j) tot += m[j];
    ssl[seg][n_l] = tot;
    __syncthreads();
    float acc = x0[n];
    for (int r = 0; r < seg; ++r) acc += ssl[r][n_l];
#pragma unroll
    for (int j = 0; j < 32; ++j) {
        Bb[(seg * 32 + j) * NN + n] = acc;               // exclusive prefix + x0
        acc += m[j];
    }
}

// ---------------------------------------------------------------------------
// K3: per (chunk,slice): role0 = M (rank collapse), role1 = Gram. 1024 blocks.
__global__ __launch_bounds__(NTHR) void k_mgram(
    const float* __restrict__ Xp, const float* __restrict__ Bb,
    const float* __restrict__ temb, const int* __restrict__ toks,
    float* __restrict__ M, float* __restrict__ Gp)
{
    __shared__ float Xs[CC * DD];
    __shared__ float Vw[CC * DD];
    __shared__ float pw[CC + 1];
    const int b = blockIdx.x, tid = threadIdx.x;
    const int c = b >> 5, q = (b >> 1) & 15, role = b & 1;
    if (role == 0 && tid <= CC) pw[tid] = powf(UDEC, (float)tid);
    for (int i = tid; i < CC * SLW; i += NTHR) {
        int s = i >> 6, n = i & 63;
        int t = c * CC + s, gn = q * SLW + n;
        Xs[swz4(s, n >> 2) * 4 + (n & 3)] = Xp[t * NN + gn] + Bb[(t >> 3) * NN + gn];
    }
    __syncthreads();
    if (role == 0) {
        for (int i = tid; i < CC * DD; i += NTHR) {
            int s = i >> 6, d = i & 63;
            Vw[swz4(s, d >> 2) * 4 + (d & 3)] =
                temb[toks[c * CC + s] * DD + d] * pw[CC - s];
        }
    }
    __syncthreads();
    const float4* Xs4 = reinterpret_cast<const float4*>(Xs);
    if (role == 0) {
        // M[d][n] = sum_s Vw[s][d] * Xs[s][n] : 4d x 4n per thread
        const int dg = tid >> 4, ng = tid & 15;
        float acc[16];
#pragma unroll
        for (int k = 0; k < 16; ++k) acc[k] = 0.f;
        const float4* Vw4 = reinterpret_cast<const float4*>(Vw);
        for (int s = 0; s < CC; ++s) {
            float4 vw = Vw4[swz4(s, dg)];
            float4 xs = Xs4[swz4(s, ng)];
            acc[0]  += vw.x*xs.x; acc[1]  += vw.x*xs.y; acc[2]  += vw.x*xs.z; acc[3]  += vw.x*xs.w;
            acc[4]  += vw.y*xs.x; acc[5]  += vw.y*xs.y; acc[6]  += vw.y*xs.z; acc[7]  += vw.y*xs.w;
            acc[8]  += vw.z*xs.x; acc[9]  += vw.z*xs.y; acc[10] += vw.z*xs.z; acc[11] += vw.z*xs.w;
            acc[12] += vw.w*xs.x; acc[13] += vw.w*xs.y; acc[14] += vw.w*xs.z; acc[15] += vw.w*xs.w;
        }
#pragma unroll
        for (int a = 0; a < 4; ++a)
            *reinterpret_cast<float4*>(&M[(c * DD + dg * 4 + a) * NN + q * SLW + ng * 4]) =
                make_float4(acc[a*4], acc[a*4+1], acc[a*4+2], acc[a*4+3]);
    } else {
        // G[t][s] = sum_n Xs[t][n]*Xs[s][n] : 4t x 4s per thread
        const int tg = tid >> 4, sg = tid & 15;
        float acc[16];
#pragma unroll
        for (int k = 0; k < 16; ++k) acc[k] = 0.f;
        for (int n4 = 0; n4 < 16; ++n4) {
            float4 xa[4], xb[4];
#pragma unroll
            for (int a = 0; a < 4; ++a) xa[a] = Xs4[swz4(tg * 4 + a, n4)];
#pragma unroll
            for (int e = 0; e < 4; ++e) xb[e] = Xs4[swz4(sg * 4 + e, n4)];
#pragma unroll
            for (int a = 0; a < 4; ++a)
#pragma unroll
                for (int e = 0; e < 4; ++e) acc[a*4+e] += DOT4(xa[a], xb[e]);
        }
        float* base = Gp + ((size_t)(c * NSL + q) * CC) * CC;
#pragma unroll
        for (int a = 0; a < 4; ++a)
            *reinterpret_cast<float4*>(base + (tg * 4 + a) * CC + sg * 4) =
                make_float4(acc[a*4], acc[a*4+1], acc[a*4+2], acc[a*4+3]);
    }
}

// ---------------------------------------------------------------------------
// K4: segmented chunk scan of rho. 1024 blocks.
__global__ __launch_bounds__(NTHR) void k_rho(
    const float* __restrict__ M, const float* __restrict__ rho0, float* __restrict__ Rho)
{
    __shared__ float ssl[4][DD + 1];
    const int b = blockIdx.x, tid = threadIdx.x;
    const int e_l = tid & 63, seg = tid >> 6;            // seg handles 8 chunks
    const int el = b * 64 + e_l;                         // 1024*64 = DD*NN
    const float uc = powf(UDEC, (float)CC);
    const float uc8 = powf(uc, 8.0f);
    float mreg[8];
#pragma unroll
    for (int j = 0; j < 8; ++j) mreg[j] = M[(size_t)(seg * 8 + j) * (DD * NN) + el];
    float ss = 0.f;
#pragma unroll
    for (int j = 0; j < 8; ++j) ss = fmaf(ss, uc, mreg[j]);
    ssl[seg][e_l] = ss;
    __syncthreads();
    float st = rho0[el];
    for (int r = 0; r < seg; ++r) st = fmaf(st, uc8, ssl[r][e_l]);
    float acc = st;
#pragma unroll
    for (int j = 0; j < 8; ++j) {
        Rho[(size_t)(seg * 8 + j) * (DD * NN) + el] = acc;
        acc = fmaf(acc, uc, mreg[j]);
    }
}

// ---------------------------------------------------------------------------
// K5: Pp[t][d] = sum_n X[t][n]*Rho[d][n], per (chunk, slice, t-half). 1024 blocks.
__global__ __launch_bounds__(NTHR) void k_inter(
    const float* __restrict__ Xp, const float* __restrict__ Bb,
    const float* __restrict__ Rho, float* __restrict__ Pp)
{
    __shared__ float Xs[32 * DD];
    __shared__ float Rs[DD * DD];
    const int b = blockIdx.x, tid = threadIdx.x;
    const int c = b >> 5, q = (b >> 1) & 15, h = b & 1;
    for (int i = tid; i < 32 * SLW; i += NTHR) {
        int s = i >> 6, n = i & 63;                      // 32 t-rows of this half
        int t = c * CC + h * 32 + s, gn = q * SLW + n;
        Xs[swz4(s, n >> 2) * 4 + (n & 3)] = Xp[t * NN + gn] + Bb[(t >> 3) * NN + gn];
    }
    for (int i = tid; i < DD * SLW; i += NTHR) {
        int s = i >> 6, n = i & 63;                      // all 64 d-rows
        int gn = q * SLW + n;
        Rs[swz4(s, n >> 2) * 4 + (n & 3)] = Rho[(size_t)(c * DD + s) * NN + gn];
    }
    __syncthreads();
    const float4* Xs4 = reinterpret_cast<const float4*>(Xs);
    const float4* Rs4 = reinterpret_cast<const float4*>(Rs);
    const int ti = tid >> 4, dg = tid & 15;              // 2 t x 4 d per thread
    float acc[8];
#pragma unroll
    for (int k = 0; k < 8; ++k) acc[k] = 0.f;
    for (int n4 = 0; n4 < 16; ++n4) {
        float4 xa[2], rv[4];
#pragma unroll
        for (int a = 0; a < 2; ++a) xa[a] = Xs4[swz4(ti * 2 + a, n4)];
#pragma unroll
        for (int e = 0; e < 4; ++e) rv[e] = Rs4[swz4(dg * 4 + e, n4)];
#pragma unroll
        for (int a = 0; a < 2; ++a)
#pragma unroll
            for (int e = 0; e < 4; ++e) acc[a*4+e] += DOT4(xa[a], rv[e]);
    }
#pragma unroll
    for (int a = 0; a < 2; ++a) {
        int trow = h * 32 + ti * 2 + a;
        *reinterpret_cast<float4*>(
            Pp + (((size_t)(c * NSL + q) * CC) + trow) * DD + dg * 4) =
            make_float4(acc[a*4], acc[a*4+1], acc[a*4+2], acc[a*4+3]);
    }
}

// ---------------------------------------------------------------------------
// K6: a* assembly + LN + y + v, per (chunk, sub): 4 tokens t = sub+16k. 512 blocks.
__global__ __launch_bounds__(NTHR) void k_out(
    const float* __restrict__ Gp, const float* __restrict__ Pp,
    const float* __restrict__ temb, const int* __restrict__ toks,
    const float* __restrict__ Xp, const float* __restrict__ Bb,
    const float* __restrict__ Dy, const float* __restrict__ E,
    float* __restrict__ ys, float* __restrict__ vs)
{
    __shared__ float VeYs[4 * NN];       // Ve[s][d]=VeYs[s*64+d], later Ys[k][n]=VeYs[k*1024+n]
    __shared__ float Gt[4][CC];
    __shared__ float Pt[4][DD];
    __shared__ float pw[CC + 1];
    __shared__ float L[4][DD];
    __shared__ float pre[4][DD + 1];
    __shared__ float mrow[4], srow[4];
    const int b = blockIdx.x, tid = threadIdx.x;
    const int c = b >> 4, sub = b & 15;
    if (tid <= CC) pw[tid] = powf(UDEC, (float)tid);
    for (int i = tid; i < CC * DD; i += NTHR) {
        int s = i >> 6, d = i & 63;
        VeYs[s * 64 + d] = temb[toks[c * CC + s] * DD + d];
    }
    {
        int k = tid >> 6, s = tid & 63;
        int t = sub + 16 * k;
        float ag = 0.f, ap = 0.f;
#pragma unroll
        for (int q = 0; q < NSL; ++q) {
            ag += Gp[((size_t)(c * NSL + q) * CC + t) * CC + s];
            ap += Pp[((size_t)(c * NSL + q) * CC + t) * DD + s];
        }
        Gt[k][s] = ag; Pt[k][s] = ap;
    }
    __syncthreads();
    {   // a* + LN, one wave per t-row
        const int tk = tid >> 6, d0 = tid & 63;
        const int t = sub + 16 * tk;
        float a = pw[t] * Pt[tk][d0];
        for (int s = 0; s < t; ++s)
            a = fmaf(pw[t - s] * Gt[tk][s], VeYs[s * 64 + d0], a);
        float sum = a;
#pragma unroll
        for (int mm = 1; mm < 64; mm <<= 1) sum += __shfl_xor(sum, mm, 64);
        float mean = sum * (1.f / DD);
        float z = a - mean;
        float vv = z * z;
#pragma unroll
        for (int mm = 1; mm < 64; mm <<= 1) vv += __shfl_xor(vv, mm, 64);
        float inv = 1.f / (sqrtf(vv * (1.f / (DD - 1))) + EPS);
        L[tk][d0] = z * inv;
    }
    __syncthreads();                                      // Ve dead -> reuse as Ys
    for (int nq = 0; nq < 4; ++nq) {
        const int n = nq * 256 + tid;
        float dyr[DD];
        const float4* dy4 = reinterpret_cast<const float4*>(Dy + n * DD);
#pragma unroll
        for (int j = 0; j < 16; ++j) {
            float4 v = dy4[j];
            dyr[4*j] = v.x; dyr[4*j+1] = v.y; dyr[4*j+2] = v.z; dyr[4*j+3] = v.w;
        }
#pragma unroll
        for (int k = 0; k < 4; ++k) {
            const float4* lr = reinterpret_cast<const float4*>(&L[k][0]);
            float a0 = 0.f, a1 = 0.f, a2 = 0.f, a3 = 0.f;
#pragma unroll
            for (int j = 0; j < 16; ++j) {
                float4 v = lr[j];
                a0 += v.x * dyr[4*j];   a1 += v.y * dyr[4*j+1];
                a2 += v.z * dyr[4*j+2]; a3 += v.w * dyr[4*j+3];
            }
            float yc = (a0 + a1) + (a2 + a3);
            int tg = c * CC + sub + 16 * k;
            float xv = Xp[tg * NN + n] + Bb[(tg >> 3) * NN + n];
            float yv = fmaxf(yc, 0.f) * fmaxf(xv, 0.f);
            ys[tg * NN + n] = yv;
            VeYs[k * NN + n] = yv;
        }
    }
    __syncthreads();
    {   // v = LN(E @ y)
        const int k = tid >> 6, d = tid & 63;
        const float4* e4 = reinterpret_cast<const float4*>(E + d * NN);
        const float4* y4 = reinterpret_cast<const float4*>(&VeYs[k * NN]);
        float a0 = 0.f, a1 = 0.f, a2 = 0.f, a3 = 0.f;
        for (int j = 0; j < NN / 4; ++j) {
            float4 ev = e4[j], yv = y4[j];
            a0 += ev.x * yv.x; a1 += ev.y * yv.y; a2 += ev.z * yv.z; a3 += ev.w * yv.w;
        }
        pre[k][d] = (a0 + a1) + (a2 + a3);
    }
    __syncthreads();
    if (tid < 4) {
        float m = 0.f;
#pragma unroll
        for (int dd2 = 0; dd2 < DD; ++dd2) m += pre[tid][dd2];
        m *= (1.f / DD);
        float v = 0.f;
#pragma unroll
        for (int dd2 = 0; dd2 < DD; ++dd2) { float z = pre[tid][dd2] - m; v += z * z; }
        mrow[tid] = m;
        srow[tid] = 1.f / (sqrtf(v * (1.f / (DD - 1))) + EPS);
    }
    __syncthreads();
    {
        int k = tid >> 6, d = tid & 63;
        vs[(c * CC + sub + 16 * k) * DD + d] = (pre[k][d] - mrow[k]) * srow[k];
    }
}

// ---------------------------------------------------------------------------
extern "C" void kernel_launch(void* const* d_in, const int* in_sizes, int n_in,
                              void* d_out, int out_size, void* d_ws, size_t ws_size,
                              hipStream_t stream) {
    (void)in_sizes; (void)n_in; (void)out_size; (void)ws_size;
    const float* E    = (const float*)d_in[0];   // [D,N]
    const float* Dx   = (const float*)d_in[1];   // [N,D]
    const float* Dy   = (const float*)d_in[2];   // [N,D]
    const float* temb = (const float*)d_in[3];   // [V,D]
    const float* x0   = (const float*)d_in[4];   // [N]
    const float* rho0 = (const float*)d_in[5];   // [D,N]
    const int*   toks = (const int*)d_in[6];     // [T]

    float* ys = (float*)d_out;                   // [T,N]
    float* vs = ys + (size_t)TT * NN;            // [T,D]

    // Workspace ~34 MiB. Pp aliases M (M dead after K4; Pp written in K5).
    float* w   = (float*)d_ws;
    float* Xp  = w;                                  // TT*NN         (8 MB)
    float* S   = Xp  + (size_t)TT * NN;              // NC2*NN        (1 MB)
    float* Bb  = S   + (size_t)NC2 * NN;             // NC2*NN        (1 MB)
    float* M   = Bb  + (size_t)NC2 * NN;             // NCH*DD*NN     (8 MB)
    float* Rho = M   + (size_t)NCH * DD * NN;        // NCH*DD*NN     (8 MB)
    float* Gp  = Rho + (size_t)NCH * DD * NN;        // NCH*NSL*CC*CC (8 MB)
    float* Pp  = M;                                  // alias

    k_xscan<<<dim3(4 * NC2),   NTHR, 0, stream>>>(Dx, temb, toks, Xp, S);
    k_base <<<dim3(32),        NTHR, 0, stream>>>(S, x0, Bb);
    k_mgram<<<dim3(NCH*NSL*2), NTHR, 0, stream>>>(Xp, Bb, temb, toks, M, Gp);
    k_rho  <<<dim3(DD*NN/64),  NTHR, 0, stream>>>(M, rho0, Rho);
    k_inter<<<dim3(NCH*NSL*2), NTHR, 0, stream>>>(Xp, Bb, Rho, Pp);
    k_out  <<<dim3(NCH*16),    NTHR, 0, stream>>>(Gp, Pp, temb, toks, Xp, Bb, Dy, E, ys, vs);
}

// Round 5
// 216.059 us; speedup vs baseline: 2.2907x; 1.0754x over previous
//
#include <hip/hip_runtime.h>
#include <math.h>

// Problem constants
#define NN 1024      // N
#define DD 64        // D
#define TT 2048      // T
#define UDEC 0.97f
#define EPS 1e-6f

// rho/a* path chunking
#define CC 64        // chunk length along t
#define NCH 32       // TT/CC
#define NSL 16       // N-slices
#define SLW 64       // NN/NSL
// X prefix-scan chunking
#define C2 8
#define NC2 256      // TT/C2

#define NTHR 256

// Swizzled [R][64] fp32 LDS tile: element (r,c) at float4-block r*16+((c>>2)^(r&15)).
__device__ __forceinline__ int swz4(int r, int c4) { return r * 16 + (c4 ^ (r & 15)); }

#define DOT4(p, q2) ((p).x*(q2).x + (p).y*(q2).y + (p).z*(q2).z + (p).w*(q2).w)

// ---------------------------------------------------------------------------
// K1: X chunk-scan, chunks of C2=8 tokens. 1024 blocks.
__global__ __launch_bounds__(NTHR) void k_xscan(
    const float* __restrict__ Dx, const float* __restrict__ temb,
    const int* __restrict__ toks, float* __restrict__ Xp, float* __restrict__ S)
{
    __shared__ float Vs[C2][DD];
    const int b = blockIdx.x, tid = threadIdx.x;
    const int cs = b >> 2, qx = b & 3;
    const int n = qx * 256 + tid;
    for (int i = tid; i < C2 * DD; i += NTHR) {
        int s = i >> 6, d = i & 63;
        Vs[s][d] = temb[toks[cs * C2 + s] * DD + d];
    }
    __syncthreads();
    float dxr[DD];
    const float4* dx4 = reinterpret_cast<const float4*>(Dx + n * DD);
#pragma unroll
    for (int j = 0; j < 16; ++j) {
        float4 v = dx4[j];
        dxr[4*j] = v.x; dxr[4*j+1] = v.y; dxr[4*j+2] = v.z; dxr[4*j+3] = v.w;
    }
    float run = 0.f;
    for (int s = 0; s < C2; ++s) {
        const float4* vr = reinterpret_cast<const float4*>(&Vs[s][0]);
        float a0 = 0.f, a1 = 0.f, a2 = 0.f, a3 = 0.f;
#pragma unroll
        for (int j = 0; j < 16; ++j) {
            float4 v = vr[j];
            a0 += v.x * dxr[4*j];     a1 += v.y * dxr[4*j+1];
            a2 += v.z * dxr[4*j+2];   a3 += v.w * dxr[4*j+3];
        }
        run += fmaxf((a0 + a1) + (a2 + a3), 0.f);
        Xp[(cs * C2 + s) * NN + n] = run;
    }
    S[cs * NN + n] = run;
}

// ---------------------------------------------------------------------------
// K2: segmented scan of 256 chunk totals -> exclusive base Bb. 32 blocks.
__global__ __launch_bounds__(NTHR) void k_base(
    const float* __restrict__ S, const float* __restrict__ x0, float* __restrict__ Bb)
{
    __shared__ float ssl[8][33];
    const int b = blockIdx.x, tid = threadIdx.x;
    const int n_l = tid & 31, seg = tid >> 5;            // 8 segs x 32 chunks
    const int n = b * 32 + n_l;
    float m[32];
#pragma unroll
    for (int j = 0; j < 32; ++j) m[j] = S[(seg * 32 + j) * NN + n];
    float tot = 0.f;
#pragma unroll
    for (int j = 0; j < 32; ++j) tot += m[j];
    ssl[seg][n_l] = tot;
    __syncthreads();
    float acc = x0[n];
    for (int r = 0; r < seg; ++r) acc += ssl[r][n_l];
#pragma unroll
    for (int j = 0; j < 32; ++j) {
        Bb[(seg * 32 + j) * NN + n] = acc;               // exclusive prefix + x0
        acc += m[j];
    }
}

// ---------------------------------------------------------------------------
// K3: per (chunk,slice): role0 = M (rank collapse), role1 = Gram. 1024 blocks.
__global__ __launch_bounds__(NTHR) void k_mgram(
    const float* __restrict__ Xp, const float* __restrict__ Bb,
    const float* __restrict__ temb, const int* __restrict__ toks,
    float* __restrict__ M, float* __restrict__ Gp)
{
    __shared__ float Xs[CC * DD];
    __shared__ float Vw[CC * DD];
    __shared__ float pw[CC + 1];
    const int b = blockIdx.x, tid = threadIdx.x;
    const int c = b >> 5, q = (b >> 1) & 15, role = b & 1;
    if (role == 0 && tid <= CC) pw[tid] = powf(UDEC, (float)tid);
    for (int i = tid; i < CC * SLW; i += NTHR) {
        int s = i >> 6, n = i & 63;
        int t = c * CC + s, gn = q * SLW + n;
        Xs[swz4(s, n >> 2) * 4 + (n & 3)] = Xp[t * NN + gn] + Bb[(t >> 3) * NN + gn];
    }
    __syncthreads();
    if (role == 0) {
        for (int i = tid; i < CC * DD; i += NTHR) {
            int s = i >> 6, d = i & 63;
            Vw[swz4(s, d >> 2) * 4 + (d & 3)] =
                temb[toks[c * CC + s] * DD + d] * pw[CC - s];
        }
    }
    __syncthreads();
    const float4* Xs4 = reinterpret_cast<const float4*>(Xs);
    if (role == 0) {
        // M[d][n] = sum_s Vw[s][d] * Xs[s][n] : 4d x 4n per thread
        const int dg = tid >> 4, ng = tid & 15;
        float acc[16];
#pragma unroll
        for (int k = 0; k < 16; ++k) acc[k] = 0.f;
        const float4* Vw4 = reinterpret_cast<const float4*>(Vw);
        for (int s = 0; s < CC; ++s) {
            float4 vw = Vw4[swz4(s, dg)];
            float4 xs = Xs4[swz4(s, ng)];
            acc[0]  += vw.x*xs.x; acc[1]  += vw.x*xs.y; acc[2]  += vw.x*xs.z; acc[3]  += vw.x*xs.w;
            acc[4]  += vw.y*xs.x; acc[5]  += vw.y*xs.y; acc[6]  += vw.y*xs.z; acc[7]  += vw.y*xs.w;
            acc[8]  += vw.z*xs.x; acc[9]  += vw.z*xs.y; acc[10] += vw.z*xs.z; acc[11] += vw.z*xs.w;
            acc[12] += vw.w*xs.x; acc[13] += vw.w*xs.y; acc[14] += vw.w*xs.z; acc[15] += vw.w*xs.w;
        }
#pragma unroll
        for (int a = 0; a < 4; ++a)
            *reinterpret_cast<float4*>(&M[(c * DD + dg * 4 + a) * NN + q * SLW + ng * 4]) =
                make_float4(acc[a*4], acc[a*4+1], acc[a*4+2], acc[a*4+3]);
    } else {
        // G[t][s] = sum_n Xs[t][n]*Xs[s][n] : 4t x 4s per thread
        const int tg = tid >> 4, sg = tid & 15;
        float acc[16];
#pragma unroll
        for (int k = 0; k < 16; ++k) acc[k] = 0.f;
        for (int n4 = 0; n4 < 16; ++n4) {
            float4 xa[4], xb[4];
#pragma unroll
            for (int a = 0; a < 4; ++a) xa[a] = Xs4[swz4(tg * 4 + a, n4)];
#pragma unroll
            for (int e = 0; e < 4; ++e) xb[e] = Xs4[swz4(sg * 4 + e, n4)];
#pragma unroll
            for (int a = 0; a < 4; ++a)
#pragma unroll
                for (int e = 0; e < 4; ++e) acc[a*4+e] += DOT4(xa[a], xb[e]);
        }
        float* base = Gp + ((size_t)(c * NSL + q) * CC) * CC;
#pragma unroll
        for (int a = 0; a < 4; ++a)
            *reinterpret_cast<float4*>(base + (tg * 4 + a) * CC + sg * 4) =
                make_float4(acc[a*4], acc[a*4+1], acc[a*4+2], acc[a*4+3]);
    }
}

// ---------------------------------------------------------------------------
// K4: segmented chunk scan of rho. 1024 blocks.
__global__ __launch_bounds__(NTHR) void k_rho(
    const float* __restrict__ M, const float* __restrict__ rho0, float* __restrict__ Rho)
{
    __shared__ float ssl[4][DD + 1];
    const int b = blockIdx.x, tid = threadIdx.x;
    const int e_l = tid & 63, seg = tid >> 6;            // seg handles 8 chunks
    const int el = b * 64 + e_l;                         // 1024*64 = DD*NN
    const float uc = powf(UDEC, (float)CC);
    const float uc8 = powf(uc, 8.0f);
    float mreg[8];
#pragma unroll
    for (int j = 0; j < 8; ++j) mreg[j] = M[(size_t)(seg * 8 + j) * (DD * NN) + el];
    float ss = 0.f;
#pragma unroll
    for (int j = 0; j < 8; ++j) ss = fmaf(ss, uc, mreg[j]);
    ssl[seg][e_l] = ss;
    __syncthreads();
    float st = rho0[el];
    for (int r = 0; r < seg; ++r) st = fmaf(st, uc8, ssl[r][e_l]);
    float acc = st;
#pragma unroll
    for (int j = 0; j < 8; ++j) {
        Rho[(size_t)(seg * 8 + j) * (DD * NN) + el] = acc;
        acc = fmaf(acc, uc, mreg[j]);
    }
}

// ---------------------------------------------------------------------------
// K5: Pp[t][d] = sum_n X[t][n]*Rho[d][n], per (chunk, slice, t-half). 1024 blocks.
__global__ __launch_bounds__(NTHR) void k_inter(
    const float* __restrict__ Xp, const float* __restrict__ Bb,
    const float* __restrict__ Rho, float* __restrict__ Pp)
{
    __shared__ float Xs[32 * DD];
    __shared__ float Rs[DD * DD];
    const int b = blockIdx.x, tid = threadIdx.x;
    const int c = b >> 5, q = (b >> 1) & 15, h = b & 1;
    for (int i = tid; i < 32 * SLW; i += NTHR) {
        int s = i >> 6, n = i & 63;                      // 32 t-rows of this half
        int t = c * CC + h * 32 + s, gn = q * SLW + n;
        Xs[swz4(s, n >> 2) * 4 + (n & 3)] = Xp[t * NN + gn] + Bb[(t >> 3) * NN + gn];
    }
    for (int i = tid; i < DD * SLW; i += NTHR) {
        int s = i >> 6, n = i & 63;                      // all 64 d-rows
        int gn = q * SLW + n;
        Rs[swz4(s, n >> 2) * 4 + (n & 3)] = Rho[(size_t)(c * DD + s) * NN + gn];
    }
    __syncthreads();
    const float4* Xs4 = reinterpret_cast<const float4*>(Xs);
    const float4* Rs4 = reinterpret_cast<const float4*>(Rs);
    const int ti = tid >> 4, dg = tid & 15;              // 2 t x 4 d per thread
    float acc[8];
#pragma unroll
    for (int k = 0; k < 8; ++k) acc[k] = 0.f;
    for (int n4 = 0; n4 < 16; ++n4) {
        float4 xa[2], rv[4];
#pragma unroll
        for (int a = 0; a < 2; ++a) xa[a] = Xs4[swz4(ti * 2 + a, n4)];
#pragma unroll
        for (int e = 0; e < 4; ++e) rv[e] = Rs4[swz4(dg * 4 + e, n4)];
#pragma unroll
        for (int a = 0; a < 2; ++a)
#pragma unroll
            for (int e = 0; e < 4; ++e) acc[a*4+e] += DOT4(xa[a], rv[e]);
    }
#pragma unroll
    for (int a = 0; a < 2; ++a) {
        int trow = h * 32 + ti * 2 + a;
        *reinterpret_cast<float4*>(
            Pp + (((size_t)(c * NSL + q) * CC) + trow) * DD + dg * 4) =
            make_float4(acc[a*4], acc[a*4+1], acc[a*4+2], acc[a*4+3]);
    }
}

// ---------------------------------------------------------------------------
// K6: a* assembly + LN only. 512 blocks, low VGPR, LNA is tiny (0.5 MB).
__global__ __launch_bounds__(NTHR) void k_astar(
    const float* __restrict__ Gp, const float* __restrict__ Pp,
    const float* __restrict__ temb, const int* __restrict__ toks,
    float* __restrict__ LNA)
{
    __shared__ float Ve[CC * DD];        // 16 KB
    __shared__ float Gt[4][CC];
    __shared__ float Pt[4][DD];
    __shared__ float pw[CC + 1];
    const int b = blockIdx.x, tid = threadIdx.x;
    const int c = b >> 4, sub = b & 15;                  // tokens t = sub + 16k, k<4
    if (tid <= CC) pw[tid] = powf(UDEC, (float)tid);
    for (int i = tid; i < CC * DD; i += NTHR) {
        int s = i >> 6, d = i & 63;
        Ve[s * 64 + d] = temb[toks[c * CC + s] * DD + d];
    }
    {
        int k = tid >> 6, s = tid & 63;
        int t = sub + 16 * k;
        float ag = 0.f, ap = 0.f;
#pragma unroll
        for (int q = 0; q < NSL; ++q) {
            ag += Gp[((size_t)(c * NSL + q) * CC + t) * CC + s];
            ap += Pp[((size_t)(c * NSL + q) * CC + t) * DD + s];
        }
        Gt[k][s] = ag; Pt[k][s] = ap;
    }
    __syncthreads();
    {   // a* + LN, one wave per t-row
        const int tk = tid >> 6, d0 = tid & 63;
        const int t = sub + 16 * tk;
        float a = pw[t] * Pt[tk][d0];
        for (int s = 0; s < t; ++s)
            a = fmaf(pw[t - s] * Gt[tk][s], Ve[s * 64 + d0], a);
        float sum = a;
#pragma unroll
        for (int mm = 1; mm < 64; mm <<= 1) sum += __shfl_xor(sum, mm, 64);
        float mean = sum * (1.f / DD);
        float z = a - mean;
        float vv = z * z;
#pragma unroll
        for (int mm = 1; mm < 64; mm <<= 1) vv += __shfl_xor(vv, mm, 64);
        float inv = 1.f / (sqrtf(vv * (1.f / (DD - 1))) + EPS);
        LNA[(c * CC + t) * DD + d0] = z * inv;
    }
}

// ---------------------------------------------------------------------------
// K7: y[t][n] = relu(dot(LNA[t], Dy[n])) * relu(x[t][n]). grid (4, 256) = 1024.
__global__ __launch_bounds__(NTHR) void k_y(
    const float* __restrict__ LNA, const float* __restrict__ Dy,
    const float* __restrict__ Xp, const float* __restrict__ Bb,
    float* __restrict__ ys)
{
    __shared__ float L[8][DD];
    const int tt = blockIdx.y;                       // 8-token tile
    const int n  = blockIdx.x * 256 + threadIdx.x;
    for (int i = threadIdx.x; i < 8 * DD; i += NTHR) L[i >> 6][i & 63] = LNA[tt * 8 * DD + i];
    __syncthreads();
    float dyr[DD];
    const float4* dy4 = reinterpret_cast<const float4*>(Dy + n * DD);
#pragma unroll
    for (int j = 0; j < 16; ++j) {
        float4 v = dy4[j];
        dyr[4*j] = v.x; dyr[4*j+1] = v.y; dyr[4*j+2] = v.z; dyr[4*j+3] = v.w;
    }
#pragma unroll
    for (int t = 0; t < 8; ++t) {
        const float4* lr = reinterpret_cast<const float4*>(&L[t][0]);
        float a0 = 0.f, a1 = 0.f, a2 = 0.f, a3 = 0.f;
#pragma unroll
        for (int j = 0; j < 16; ++j) {
            float4 v = lr[j];
            a0 += v.x * dyr[4*j];   a1 += v.y * dyr[4*j+1];
            a2 += v.z * dyr[4*j+2]; a3 += v.w * dyr[4*j+3];
        }
        float yc = (a0 + a1) + (a2 + a3);
        int tg = tt * 8 + t;
        float xv = Xp[tg * NN + n] + Bb[(tg >> 3) * NN + n];
        ys[tg * NN + n] = fmaxf(yc, 0.f) * fmaxf(xv, 0.f);
    }
}

// ---------------------------------------------------------------------------
// K8: vs[t] = LN(E @ y[t]), 4-token tiles. 512 blocks, 16 KB LDS, low VGPR.
__global__ __launch_bounds__(NTHR) void k_v(
    const float* __restrict__ ys, const float* __restrict__ E, float* __restrict__ vs)
{
    __shared__ float Ys[4][NN];          // 16 KB
    __shared__ float pre[4][DD + 1];
    __shared__ float mrow[4], srow[4];
    const int tt = blockIdx.x, tid = threadIdx.x;
    for (int i = tid; i < 4 * NN; i += NTHR) Ys[i >> 10][i & 1023] = ys[tt * 4 * NN + i];
    __syncthreads();
    {
        const int k = tid >> 6, d = tid & 63;
        const float4* e4 = reinterpret_cast<const float4*>(E + d * NN);
        const float4* y4 = reinterpret_cast<const float4*>(&Ys[k][0]);
        float a0 = 0.f, a1 = 0.f, a2 = 0.f, a3 = 0.f;
        for (int j = 0; j < NN / 4; ++j) {
            float4 ev = e4[j], yv = y4[j];
            a0 += ev.x * yv.x; a1 += ev.y * yv.y; a2 += ev.z * yv.z; a3 += ev.w * yv.w;
        }
        pre[k][d] = (a0 + a1) + (a2 + a3);
    }
    __syncthreads();
    if (tid < 4) {
        float m = 0.f;
#pragma unroll
        for (int dd2 = 0; dd2 < DD; ++dd2) m += pre[tid][dd2];
        m *= (1.f / DD);
        float v = 0.f;
#pragma unroll
        for (int dd2 = 0; dd2 < DD; ++dd2) { float z = pre[tid][dd2] - m; v += z * z; }
        mrow[tid] = m;
        srow[tid] = 1.f / (sqrtf(v * (1.f / (DD - 1))) + EPS);
    }
    __syncthreads();
    {
        int k = tid >> 6, d = tid & 63;
        vs[(tt * 4 + k) * DD + d] = (pre[k][d] - mrow[k]) * srow[k];
    }
}

// ---------------------------------------------------------------------------
extern "C" void kernel_launch(void* const* d_in, const int* in_sizes, int n_in,
                              void* d_out, int out_size, void* d_ws, size_t ws_size,
                              hipStream_t stream) {
    (void)in_sizes; (void)n_in; (void)out_size; (void)ws_size;
    const float* E    = (const float*)d_in[0];   // [D,N]
    const float* Dx   = (const float*)d_in[1];   // [N,D]
    const float* Dy   = (const float*)d_in[2];   // [N,D]
    const float* temb = (const float*)d_in[3];   // [V,D]
    const float* x0   = (const float*)d_in[4];   // [N]
    const float* rho0 = (const float*)d_in[5];   // [D,N]
    const int*   toks = (const int*)d_in[6];     // [T]

    float* ys = (float*)d_out;                   // [T,N]
    float* vs = ys + (size_t)TT * NN;            // [T,D]

    // Workspace ~34.5 MiB. Pp aliases M (M dead after K4; Pp written in K5).
    float* w   = (float*)d_ws;
    float* Xp  = w;                                  // TT*NN         (8 MB)
    float* S   = Xp  + (size_t)TT * NN;              // NC2*NN        (1 MB)
    float* Bb  = S   + (size_t)NC2 * NN;             // NC2*NN        (1 MB)
    float* M   = Bb  + (size_t)NC2 * NN;             // NCH*DD*NN     (8 MB)
    float* Rho = M   + (size_t)NCH * DD * NN;        // NCH*DD*NN     (8 MB)
    float* Gp  = Rho + (size_t)NCH * DD * NN;        // NCH*NSL*CC*CC (8 MB)
    float* LNA = Gp  + (size_t)NCH * NSL * CC * CC;  // TT*DD         (0.5 MB)
    float* Pp  = M;                                  // alias

    k_xscan<<<dim3(4 * NC2),   NTHR, 0, stream>>>(Dx, temb, toks, Xp, S);
    k_base <<<dim3(32),        NTHR, 0, stream>>>(S, x0, Bb);
    k_mgram<<<dim3(NCH*NSL*2), NTHR, 0, stream>>>(Xp, Bb, temb, toks, M, Gp);
    k_rho  <<<dim3(DD*NN/64),  NTHR, 0, stream>>>(M, rho0, Rho);
    k_inter<<<dim3(NCH*NSL*2), NTHR, 0, stream>>>(Xp, Bb, Rho, Pp);
    k_astar<<<dim3(NCH*16),    NTHR, 0, stream>>>(Gp, Pp, temb, toks, LNA);
    k_y    <<<dim3(4, TT/8),   NTHR, 0, stream>>>(LNA, Dy, Xp, Bb, ys);
    k_v    <<<dim3(TT/4),      NTHR, 0, stream>>>(ys, E, vs);
}

// Round 6
// 176.089 us; speedup vs baseline: 2.8107x; 1.2270x over previous
//
#include <hip/hip_runtime.h>
#include <math.h>

// Problem constants
#define NN 1024      // N
#define DD 64        // D
#define TT 2048      // T
#define UDEC 0.97f
#define EPS 1e-6f

// rho/a* path chunking
#define CC 64        // chunk length along t
#define NCH 32       // TT/CC
#define NSL 16       // N-slices
#define SLW 64       // NN/NSL
// X prefix-scan chunking
#define C2 8
#define NC2 256      // TT/C2

#define NTHR 256

// Swizzled [R][64] fp32 LDS tile: element (r,c) at float4-block r*16+((c>>2)^(r&15)).
__device__ __forceinline__ int swz4(int r, int c4) { return r * 16 + (c4 ^ (r & 15)); }

#define DOT4(p, q2) ((p).x*(q2).x + (p).y*(q2).y + (p).z*(q2).z + (p).w*(q2).w)

// ---------------------------------------------------------------------------
// K1: X chunk-scan, chunks of C2=8 tokens. 1024 blocks.
__global__ __launch_bounds__(NTHR) void k_xscan(
    const float* __restrict__ Dx, const float* __restrict__ temb,
    const int* __restrict__ toks, float* __restrict__ Xp, float* __restrict__ S)
{
    __shared__ float Vs[C2][DD];
    const int b = blockIdx.x, tid = threadIdx.x;
    const int cs = b >> 2, qx = b & 3;
    const int n = qx * 256 + tid;
    for (int i = tid; i < C2 * DD; i += NTHR) {
        int s = i >> 6, d = i & 63;
        Vs[s][d] = temb[toks[cs * C2 + s] * DD + d];
    }
    __syncthreads();
    float dxr[DD];
    const float4* dx4 = reinterpret_cast<const float4*>(Dx + n * DD);
#pragma unroll
    for (int j = 0; j < 16; ++j) {
        float4 v = dx4[j];
        dxr[4*j] = v.x; dxr[4*j+1] = v.y; dxr[4*j+2] = v.z; dxr[4*j+3] = v.w;
    }
    float run = 0.f;
    for (int s = 0; s < C2; ++s) {
        const float4* vr = reinterpret_cast<const float4*>(&Vs[s][0]);
        float a0 = 0.f, a1 = 0.f, a2 = 0.f, a3 = 0.f;
#pragma unroll
        for (int j = 0; j < 16; ++j) {
            float4 v = vr[j];
            a0 += v.x * dxr[4*j];     a1 += v.y * dxr[4*j+1];
            a2 += v.z * dxr[4*j+2];   a3 += v.w * dxr[4*j+3];
        }
        run += fmaxf((a0 + a1) + (a2 + a3), 0.f);
        Xp[(cs * C2 + s) * NN + n] = run;
    }
    S[cs * NN + n] = run;
}

// ---------------------------------------------------------------------------
// K2: blocks 0..31: segmented scan of chunk totals -> Bb.
//     blocks 32..95: transpose E[D][N] -> Et4 [N/4][D] float4 (for coalesced k_v).
__global__ __launch_bounds__(NTHR) void k_base(
    const float* __restrict__ S, const float* __restrict__ x0, float* __restrict__ Bb,
    const float* __restrict__ E, float* __restrict__ Et4)
{
    const int b = blockIdx.x, tid = threadIdx.x;
    if (b < 32) {
        __shared__ float ssl[8][33];
        const int n_l = tid & 31, seg = tid >> 5;        // 8 segs x 32 chunks
        const int n = b * 32 + n_l;
        float m[32];
#pragma unroll
        for (int j = 0; j < 32; ++j) m[j] = S[(seg * 32 + j) * NN + n];
        float tot = 0.f;
#pragma unroll
        for (int j = 0; j < 32; ++j) tot += m[j];
        ssl[seg][n_l] = tot;
        __syncthreads();
        float acc = x0[n];
        for (int r = 0; r < seg; ++r) acc += ssl[r][n_l];
#pragma unroll
        for (int j = 0; j < 32; ++j) {
            Bb[(seg * 32 + j) * NN + n] = acc;           // exclusive prefix + x0
            acc += m[j];
        }
    } else {
        // Et4 float4-index fi = n4*64 + d  <-  E4[d*256 + n4]
        // (gather reads, coalesced 1KB/wave writes; 256 KB one-shot)
        const int fi = (b - 32) * NTHR + tid;            // 0..16383
        const int n4 = fi >> 6, d = fi & 63;
        reinterpret_cast<float4*>(Et4)[fi] =
            reinterpret_cast<const float4*>(E)[d * (NN / 4) + n4];
    }
}

// ---------------------------------------------------------------------------
// K3: per (chunk,slice): role0 = M (rank collapse), role1 = Gram. 1024 blocks.
__global__ __launch_bounds__(NTHR) void k_mgram(
    const float* __restrict__ Xp, const float* __restrict__ Bb,
    const float* __restrict__ temb, const int* __restrict__ toks,
    float* __restrict__ M, float* __restrict__ Gp)
{
    __shared__ float Xs[CC * DD];
    __shared__ float Vw[CC * DD];
    __shared__ float pw[CC + 1];
    const int b = blockIdx.x, tid = threadIdx.x;
    const int c = b >> 5, q = (b >> 1) & 15, role = b & 1;
    if (role == 0 && tid <= CC) pw[tid] = powf(UDEC, (float)tid);
    for (int i = tid; i < CC * SLW; i += NTHR) {
        int s = i >> 6, n = i & 63;
        int t = c * CC + s, gn = q * SLW + n;
        Xs[swz4(s, n >> 2) * 4 + (n & 3)] = Xp[t * NN + gn] + Bb[(t >> 3) * NN + gn];
    }
    __syncthreads();
    if (role == 0) {
        for (int i = tid; i < CC * DD; i += NTHR) {
            int s = i >> 6, d = i & 63;
            Vw[swz4(s, d >> 2) * 4 + (d & 3)] =
                temb[toks[c * CC + s] * DD + d] * pw[CC - s];
        }
    }
    __syncthreads();
    const float4* Xs4 = reinterpret_cast<const float4*>(Xs);
    if (role == 0) {
        // M[d][n] = sum_s Vw[s][d] * Xs[s][n] : 4d x 4n per thread
        const int dg = tid >> 4, ng = tid & 15;
        float acc[16];
#pragma unroll
        for (int k = 0; k < 16; ++k) acc[k] = 0.f;
        const float4* Vw4 = reinterpret_cast<const float4*>(Vw);
        for (int s = 0; s < CC; ++s) {
            float4 vw = Vw4[swz4(s, dg)];
            float4 xs = Xs4[swz4(s, ng)];
            acc[0]  += vw.x*xs.x; acc[1]  += vw.x*xs.y; acc[2]  += vw.x*xs.z; acc[3]  += vw.x*xs.w;
            acc[4]  += vw.y*xs.x; acc[5]  += vw.y*xs.y; acc[6]  += vw.y*xs.z; acc[7]  += vw.y*xs.w;
            acc[8]  += vw.z*xs.x; acc[9]  += vw.z*xs.y; acc[10] += vw.z*xs.z; acc[11] += vw.z*xs.w;
            acc[12] += vw.w*xs.x; acc[13] += vw.w*xs.y; acc[14] += vw.w*xs.z; acc[15] += vw.w*xs.w;
        }
#pragma unroll
        for (int a = 0; a < 4; ++a)
            *reinterpret_cast<float4*>(&M[(c * DD + dg * 4 + a) * NN + q * SLW + ng * 4]) =
                make_float4(acc[a*4], acc[a*4+1], acc[a*4+2], acc[a*4+3]);
    } else {
        // G[t][s] = sum_n Xs[t][n]*Xs[s][n] : 4t x 4s per thread
        const int tg = tid >> 4, sg = tid & 15;
        float acc[16];
#pragma unroll
        for (int k = 0; k < 16; ++k) acc[k] = 0.f;
        for (int n4 = 0; n4 < 16; ++n4) {
            float4 xa[4], xb[4];
#pragma unroll
            for (int a = 0; a < 4; ++a) xa[a] = Xs4[swz4(tg * 4 + a, n4)];
#pragma unroll
            for (int e = 0; e < 4; ++e) xb[e] = Xs4[swz4(sg * 4 + e, n4)];
#pragma unroll
            for (int a = 0; a < 4; ++a)
#pragma unroll
                for (int e = 0; e < 4; ++e) acc[a*4+e] += DOT4(xa[a], xb[e]);
        }
        float* base = Gp + ((size_t)(c * NSL + q) * CC) * CC;
#pragma unroll
        for (int a = 0; a < 4; ++a)
            *reinterpret_cast<float4*>(base + (tg * 4 + a) * CC + sg * 4) =
                make_float4(acc[a*4], acc[a*4+1], acc[a*4+2], acc[a*4+3]);
    }
}

// ---------------------------------------------------------------------------
// K4: segmented chunk scan of rho. 1024 blocks.
__global__ __launch_bounds__(NTHR) void k_rho(
    const float* __restrict__ M, const float* __restrict__ rho0, float* __restrict__ Rho)
{
    __shared__ float ssl[4][DD + 1];
    const int b = blockIdx.x, tid = threadIdx.x;
    const int e_l = tid & 63, seg = tid >> 6;            // seg handles 8 chunks
    const int el = b * 64 + e_l;                         // 1024*64 = DD*NN
    const float uc = powf(UDEC, (float)CC);
    const float uc8 = powf(uc, 8.0f);
    float mreg[8];
#pragma unroll
    for (int j = 0; j < 8; ++j) mreg[j] = M[(size_t)(seg * 8 + j) * (DD * NN) + el];
    float ss = 0.f;
#pragma unroll
    for (int j = 0; j < 8; ++j) ss = fmaf(ss, uc, mreg[j]);
    ssl[seg][e_l] = ss;
    __syncthreads();
    float st = rho0[el];
    for (int r = 0; r < seg; ++r) st = fmaf(st, uc8, ssl[r][e_l]);
    float acc = st;
#pragma unroll
    for (int j = 0; j < 8; ++j) {
        Rho[(size_t)(seg * 8 + j) * (DD * NN) + el] = acc;
        acc = fmaf(acc, uc, mreg[j]);
    }
}

// ---------------------------------------------------------------------------
// K5: Pp[t][d] = sum_n X[t][n]*Rho[d][n], per (chunk, slice, t-half). 1024 blocks.
__global__ __launch_bounds__(NTHR) void k_inter(
    const float* __restrict__ Xp, const float* __restrict__ Bb,
    const float* __restrict__ Rho, float* __restrict__ Pp)
{
    __shared__ float Xs[32 * DD];
    __shared__ float Rs[DD * DD];
    const int b = blockIdx.x, tid = threadIdx.x;
    const int c = b >> 5, q = (b >> 1) & 15, h = b & 1;
    for (int i = tid; i < 32 * SLW; i += NTHR) {
        int s = i >> 6, n = i & 63;                      // 32 t-rows of this half
        int t = c * CC + h * 32 + s, gn = q * SLW + n;
        Xs[swz4(s, n >> 2) * 4 + (n & 3)] = Xp[t * NN + gn] + Bb[(t >> 3) * NN + gn];
    }
    for (int i = tid; i < DD * SLW; i += NTHR) {
        int s = i >> 6, n = i & 63;                      // all 64 d-rows
        int gn = q * SLW + n;
        Rs[swz4(s, n >> 2) * 4 + (n & 3)] = Rho[(size_t)(c * DD + s) * NN + gn];
    }
    __syncthreads();
    const float4* Xs4 = reinterpret_cast<const float4*>(Xs);
    const float4* Rs4 = reinterpret_cast<const float4*>(Rs);
    const int ti = tid >> 4, dg = tid & 15;              // 2 t x 4 d per thread
    float acc[8];
#pragma unroll
    for (int k = 0; k < 8; ++k) acc[k] = 0.f;
    for (int n4 = 0; n4 < 16; ++n4) {
        float4 xa[2], rv[4];
#pragma unroll
        for (int a = 0; a < 2; ++a) xa[a] = Xs4[swz4(ti * 2 + a, n4)];
#pragma unroll
        for (int e = 0; e < 4; ++e) rv[e] = Rs4[swz4(dg * 4 + e, n4)];
#pragma unroll
        for (int a = 0; a < 2; ++a)
#pragma unroll
            for (int e = 0; e < 4; ++e) acc[a*4+e] += DOT4(xa[a], rv[e]);
    }
#pragma unroll
    for (int a = 0; a < 2; ++a) {
        int trow = h * 32 + ti * 2 + a;
        *reinterpret_cast<float4*>(
            Pp + (((size_t)(c * NSL + q) * CC) + trow) * DD + dg * 4) =
            make_float4(acc[a*4], acc[a*4+1], acc[a*4+2], acc[a*4+3]);
    }
}

// ---------------------------------------------------------------------------
// K6: a* assembly + LN only. 512 blocks.
__global__ __launch_bounds__(NTHR) void k_astar(
    const float* __restrict__ Gp, const float* __restrict__ Pp,
    const float* __restrict__ temb, const int* __restrict__ toks,
    float* __restrict__ LNA)
{
    __shared__ float Ve[CC * DD];        // 16 KB
    __shared__ float Gt[4][CC];
    __shared__ float Pt[4][DD];
    __shared__ float pw[CC + 1];
    const int b = blockIdx.x, tid = threadIdx.x;
    const int c = b >> 4, sub = b & 15;                  // tokens t = sub + 16k, k<4
    if (tid <= CC) pw[tid] = powf(UDEC, (float)tid);
    for (int i = tid; i < CC * DD; i += NTHR) {
        int s = i >> 6, d = i & 63;
        Ve[s * 64 + d] = temb[toks[c * CC + s] * DD + d];
    }
    {
        int k = tid >> 6, s = tid & 63;
        int t = sub + 16 * k;
        float ag = 0.f, ap = 0.f;
#pragma unroll
        for (int q = 0; q < NSL; ++q) {
            ag += Gp[((size_t)(c * NSL + q) * CC + t) * CC + s];
            ap += Pp[((size_t)(c * NSL + q) * CC + t) * DD + s];
        }
        Gt[k][s] = ag; Pt[k][s] = ap;
    }
    __syncthreads();
    {   // a* + LN, one wave per t-row
        const int tk = tid >> 6, d0 = tid & 63;
        const int t = sub + 16 * tk;
        float a = pw[t] * Pt[tk][d0];
        for (int s = 0; s < t; ++s)
            a = fmaf(pw[t - s] * Gt[tk][s], Ve[s * 64 + d0], a);
        float sum = a;
#pragma unroll
        for (int mm = 1; mm < 64; mm <<= 1) sum += __shfl_xor(sum, mm, 64);
        float mean = sum * (1.f / DD);
        float z = a - mean;
        float vv = z * z;
#pragma unroll
        for (int mm = 1; mm < 64; mm <<= 1) vv += __shfl_xor(vv, mm, 64);
        float inv = 1.f / (sqrtf(vv * (1.f / (DD - 1))) + EPS);
        LNA[(c * CC + t) * DD + d0] = z * inv;
    }
}

// ---------------------------------------------------------------------------
// K7: y[t][n] = relu(dot(LNA[t], Dy[n])) * relu(x[t][n]). grid (4, 256) = 1024.
__global__ __launch_bounds__(NTHR) void k_y(
    const float* __restrict__ LNA, const float* __restrict__ Dy,
    const float* __restrict__ Xp, const float* __restrict__ Bb,
    float* __restrict__ ys)
{
    __shared__ float L[8][DD];
    const int tt = blockIdx.y;                       // 8-token tile
    const int n  = blockIdx.x * 256 + threadIdx.x;
    for (int i = threadIdx.x; i < 8 * DD; i += NTHR) L[i >> 6][i & 63] = LNA[tt * 8 * DD + i];
    __syncthreads();
    float dyr[DD];
    const float4* dy4 = reinterpret_cast<const float4*>(Dy + n * DD);
#pragma unroll
    for (int j = 0; j < 16; ++j) {
        float4 v = dy4[j];
        dyr[4*j] = v.x; dyr[4*j+1] = v.y; dyr[4*j+2] = v.z; dyr[4*j+3] = v.w;
    }
#pragma unroll
    for (int t = 0; t < 8; ++t) {
        const float4* lr = reinterpret_cast<const float4*>(&L[t][0]);
        float a0 = 0.f, a1 = 0.f, a2 = 0.f, a3 = 0.f;
#pragma unroll
        for (int j = 0; j < 16; ++j) {
            float4 v = lr[j];
            a0 += v.x * dyr[4*j];   a1 += v.y * dyr[4*j+1];
            a2 += v.z * dyr[4*j+2]; a3 += v.w * dyr[4*j+3];
        }
        float yc = (a0 + a1) + (a2 + a3);
        int tg = tt * 8 + t;
        float xv = Xp[tg * NN + n] + Bb[(tg >> 3) * NN + n];
        ys[tg * NN + n] = fmaxf(yc, 0.f) * fmaxf(xv, 0.f);
    }
}

// ---------------------------------------------------------------------------
// K8: vs[t] = LN(E @ y[t]) via transposed Et4, split-K across waves.
//     512 blocks x 4 tokens; wave w owns K-quarter w: Et streamed once/block,
//     fully coalesced (1 KB/wave/instr). LDS reduce + LN tail.
__global__ __launch_bounds__(NTHR) void k_v(
    const float* __restrict__ ys, const float* __restrict__ Et4, float* __restrict__ vs)
{
    __shared__ float Ys[4][NN];          // 16 KB
    __shared__ float pre4[4][4][DD];     // [wave][token][d], 4 KB
    __shared__ float pre[4][DD + 1];
    __shared__ float mrow[4], srow[4];
    const int tt = blockIdx.x, tid = threadIdx.x;
    for (int i = tid; i < 4 * NN; i += NTHR) Ys[i >> 10][i & 1023] = ys[tt * 4 * NN + i];
    __syncthreads();
    const int w = tid >> 6, d = tid & 63;
    float a0 = 0.f, a1 = 0.f, a2 = 0.f, a3 = 0.f;
    const float4* et = reinterpret_cast<const float4*>(Et4) + (size_t)w * 64 * DD + d;
#pragma unroll 4
    for (int i = 0; i < 64; ++i) {
        float4 ev = et[(size_t)i * DD];              // coalesced: lanes d consecutive
        const int n4g = (w * 64 + i) * 4;
        float4 y0 = *reinterpret_cast<const float4*>(&Ys[0][n4g]);   // broadcast
        float4 y1 = *reinterpret_cast<const float4*>(&Ys[1][n4g]);
        float4 y2 = *reinterpret_cast<const float4*>(&Ys[2][n4g]);
        float4 y3 = *reinterpret_cast<const float4*>(&Ys[3][n4g]);
        a0 += DOT4(ev, y0); a1 += DOT4(ev, y1);
        a2 += DOT4(ev, y2); a3 += DOT4(ev, y3);
    }
    pre4[w][0][d] = a0; pre4[w][1][d] = a1;
    pre4[w][2][d] = a2; pre4[w][3][d] = a3;
    __syncthreads();
    {
        const int k = tid >> 6, dd = tid & 63;
        pre[k][dd] = pre4[0][k][dd] + pre4[1][k][dd] + pre4[2][k][dd] + pre4[3][k][dd];
    }
    __syncthreads();
    if (tid < 4) {
        float m = 0.f;
#pragma unroll
        for (int dd2 = 0; dd2 < DD; ++dd2) m += pre[tid][dd2];
        m *= (1.f / DD);
        float v = 0.f;
#pragma unroll
        for (int dd2 = 0; dd2 < DD; ++dd2) { float z = pre[tid][dd2] - m; v += z * z; }
        mrow[tid] = m;
        srow[tid] = 1.f / (sqrtf(v * (1.f / (DD - 1))) + EPS);
    }
    __syncthreads();
    {
        int k = tid >> 6, dd = tid & 63;
        vs[(tt * 4 + k) * DD + dd] = (pre[k][dd] - mrow[k]) * srow[k];
    }
}

// ---------------------------------------------------------------------------
extern "C" void kernel_launch(void* const* d_in, const int* in_sizes, int n_in,
                              void* d_out, int out_size, void* d_ws, size_t ws_size,
                              hipStream_t stream) {
    (void)in_sizes; (void)n_in; (void)out_size; (void)ws_size;
    const float* E    = (const float*)d_in[0];   // [D,N]
    const float* Dx   = (const float*)d_in[1];   // [N,D]
    const float* Dy   = (const float*)d_in[2];   // [N,D]
    const float* temb = (const float*)d_in[3];   // [V,D]
    const float* x0   = (const float*)d_in[4];   // [N]
    const float* rho0 = (const float*)d_in[5];   // [D,N]
    const int*   toks = (const int*)d_in[6];     // [T]

    float* ys = (float*)d_out;                   // [T,N]
    float* vs = ys + (size_t)TT * NN;            // [T,D]

    // Workspace ~35 MiB. Pp aliases M (M dead after K4; Pp written in K5).
    float* w   = (float*)d_ws;
    float* Xp  = w;                                  // TT*NN         (8 MB)
    float* S   = Xp  + (size_t)TT * NN;              // NC2*NN        (1 MB)
    float* Bb  = S   + (size_t)NC2 * NN;             // NC2*NN        (1 MB)
    float* M   = Bb  + (size_t)NC2 * NN;             // NCH*DD*NN     (8 MB)
    float* Rho = M   + (size_t)NCH * DD * NN;        // NCH*DD*NN     (8 MB)
    float* Gp  = Rho + (size_t)NCH * DD * NN;        // NCH*NSL*CC*CC (8 MB)
    float* LNA = Gp  + (size_t)NCH * NSL * CC * CC;  // TT*DD         (0.5 MB)
    float* Et4 = LNA + (size_t)TT * DD;              // NN*DD         (0.25 MB)
    float* Pp  = M;                                  // alias

    k_xscan<<<dim3(4 * NC2),   NTHR, 0, stream>>>(Dx, temb, toks, Xp, S);
    k_base <<<dim3(96),        NTHR, 0, stream>>>(S, x0, Bb, E, Et4);
    k_mgram<<<dim3(NCH*NSL*2), NTHR, 0, stream>>>(Xp, Bb, temb, toks, M, Gp);
    k_rho  <<<dim3(DD*NN/64),  NTHR, 0, stream>>>(M, rho0, Rho);
    k_inter<<<dim3(NCH*NSL*2), NTHR, 0, stream>>>(Xp, Bb, Rho, Pp);
    k_astar<<<dim3(NCH*16),    NTHR, 0, stream>>>(Gp, Pp, temb, toks, LNA);
    k_y    <<<dim3(4, TT/8),   NTHR, 0, stream>>>(LNA, Dy, Xp, Bb, ys);
    k_v    <<<dim3(TT/4),      NTHR, 0, stream>>>(ys, Et4, vs);
}

// Round 7
// 167.791 us; speedup vs baseline: 2.9496x; 1.0495x over previous
//
#include <hip/hip_runtime.h>
#include <math.h>

// Problem constants
#define NN 1024      // N
#define DD 64        // D
#define TT 2048      // T
#define UDEC 0.97f
#define EPS 1e-6f

// rho/a* path chunking
#define CC 64        // chunk length along t
#define NCH 32       // TT/CC
#define NSL 16       // N-slices
#define SLW 64       // NN/NSL
// X prefix-scan chunking
#define C2 8
#define NC2 256      // TT/C2

#define NTHR 256

// Swizzled [R][64] fp32 LDS tile: element (r,c) at float4-block r*16+((c>>2)^(r&15)).
// float4 blocks stay contiguous -> staging can use b128 writes.
__device__ __forceinline__ int swz4(int r, int c4) { return r * 16 + (c4 ^ (r & 15)); }

#define DOT4(p, q2) ((p).x*(q2).x + (p).y*(q2).y + (p).z*(q2).z + (p).w*(q2).w)
#define F4ADD(a, b) make_float4((a).x+(b).x, (a).y+(b).y, (a).z+(b).z, (a).w+(b).w)

// ---------------------------------------------------------------------------
// K1: X chunk-scan, chunks of C2=8 tokens. 1024 blocks.
__global__ __launch_bounds__(NTHR) void k_xscan(
    const float* __restrict__ Dx, const float* __restrict__ temb,
    const int* __restrict__ toks, float* __restrict__ Xp, float* __restrict__ S)
{
    __shared__ float Vs[C2][DD];
    const int b = blockIdx.x, tid = threadIdx.x;
    const int cs = b >> 2, qx = b & 3;
    const int n = qx * 256 + tid;
    for (int i = tid; i < C2 * DD / 4; i += NTHR) {          // float4 staging
        int s = i >> 4, d4 = i & 15;
        reinterpret_cast<float4*>(&Vs[s][0])[d4] =
            reinterpret_cast<const float4*>(temb + toks[cs * C2 + s] * DD)[d4];
    }
    __syncthreads();
    float dxr[DD];
    const float4* dx4 = reinterpret_cast<const float4*>(Dx + n * DD);
#pragma unroll
    for (int j = 0; j < 16; ++j) {
        float4 v = dx4[j];
        dxr[4*j] = v.x; dxr[4*j+1] = v.y; dxr[4*j+2] = v.z; dxr[4*j+3] = v.w;
    }
    float run = 0.f;
    for (int s = 0; s < C2; ++s) {
        const float4* vr = reinterpret_cast<const float4*>(&Vs[s][0]);
        float a0 = 0.f, a1 = 0.f, a2 = 0.f, a3 = 0.f;
#pragma unroll
        for (int j = 0; j < 16; ++j) {
            float4 v = vr[j];
            a0 += v.x * dxr[4*j];     a1 += v.y * dxr[4*j+1];
            a2 += v.z * dxr[4*j+2];   a3 += v.w * dxr[4*j+3];
        }
        run += fmaxf((a0 + a1) + (a2 + a3), 0.f);
        Xp[(cs * C2 + s) * NN + n] = run;
    }
    S[cs * NN + n] = run;
}

// ---------------------------------------------------------------------------
// K2: blocks 0..31: segmented scan of chunk totals -> Bb.
//     blocks 32..95: transpose E[D][N] -> Et4 [N/4][D] float4 (for coalesced k_v).
__global__ __launch_bounds__(NTHR) void k_base(
    const float* __restrict__ S, const float* __restrict__ x0, float* __restrict__ Bb,
    const float* __restrict__ E, float* __restrict__ Et4)
{
    const int b = blockIdx.x, tid = threadIdx.x;
    if (b < 32) {
        __shared__ float ssl[8][33];
        const int n_l = tid & 31, seg = tid >> 5;        // 8 segs x 32 chunks
        const int n = b * 32 + n_l;
        float m[32];
#pragma unroll
        for (int j = 0; j < 32; ++j) m[j] = S[(seg * 32 + j) * NN + n];
        float tot = 0.f;
#pragma unroll
        for (int j = 0; j < 32; ++j) tot += m[j];
        ssl[seg][n_l] = tot;
        __syncthreads();
        float acc = x0[n];
        for (int r = 0; r < seg; ++r) acc += ssl[r][n_l];
#pragma unroll
        for (int j = 0; j < 32; ++j) {
            Bb[(seg * 32 + j) * NN + n] = acc;           // exclusive prefix + x0
            acc += m[j];
        }
    } else {
        const int fi = (b - 32) * NTHR + tid;            // 0..16383
        const int n4 = fi >> 6, d = fi & 63;
        reinterpret_cast<float4*>(Et4)[fi] =
            reinterpret_cast<const float4*>(E)[d * (NN / 4) + n4];
    }
}

// ---------------------------------------------------------------------------
// K3: per (chunk,slice): role0 = M (rank collapse), role1 = Gram. 1024 blocks.
__global__ __launch_bounds__(NTHR) void k_mgram(
    const float* __restrict__ Xp, const float* __restrict__ Bb,
    const float* __restrict__ temb, const int* __restrict__ toks,
    float* __restrict__ M, float* __restrict__ Gp)
{
    __shared__ float Xs[CC * DD];
    __shared__ float Vw[CC * DD];
    __shared__ float pw[CC + 1];
    const int b = blockIdx.x, tid = threadIdx.x;
    const int c = b >> 5, q = (b >> 1) & 15, role = b & 1;
    if (role == 0 && tid <= CC) pw[tid] = powf(UDEC, (float)tid);
    for (int i = tid; i < CC * SLW / 4; i += NTHR) {     // float4 staging, 4 iters
        int s = i >> 4, n4 = i & 15;
        int t = c * CC + s;
        float4 xv = *reinterpret_cast<const float4*>(&Xp[t * NN + q * SLW + n4 * 4]);
        float4 bv = *reinterpret_cast<const float4*>(&Bb[(t >> 3) * NN + q * SLW + n4 * 4]);
        reinterpret_cast<float4*>(Xs)[swz4(s, n4)] = F4ADD(xv, bv);
    }
    __syncthreads();
    if (role == 0) {
        for (int i = tid; i < CC * DD / 4; i += NTHR) {  // float4 staging, 4 iters
            int s = i >> 4, d4 = i & 15;
            float4 v = reinterpret_cast<const float4*>(temb + toks[c * CC + s] * DD)[d4];
            float wv = pw[CC - s];
            reinterpret_cast<float4*>(Vw)[swz4(s, d4)] =
                make_float4(v.x * wv, v.y * wv, v.z * wv, v.w * wv);
        }
    }
    __syncthreads();
    const float4* Xs4 = reinterpret_cast<const float4*>(Xs);
    if (role == 0) {
        // M[d][n] = sum_s Vw[s][d] * Xs[s][n] : 4d x 4n per thread
        const int dg = tid >> 4, ng = tid & 15;
        float acc[16];
#pragma unroll
        for (int k = 0; k < 16; ++k) acc[k] = 0.f;
        const float4* Vw4 = reinterpret_cast<const float4*>(Vw);
        for (int s = 0; s < CC; ++s) {
            float4 vw = Vw4[swz4(s, dg)];
            float4 xs = Xs4[swz4(s, ng)];
            acc[0]  += vw.x*xs.x; acc[1]  += vw.x*xs.y; acc[2]  += vw.x*xs.z; acc[3]  += vw.x*xs.w;
            acc[4]  += vw.y*xs.x; acc[5]  += vw.y*xs.y; acc[6]  += vw.y*xs.z; acc[7]  += vw.y*xs.w;
            acc[8]  += vw.z*xs.x; acc[9]  += vw.z*xs.y; acc[10] += vw.z*xs.z; acc[11] += vw.z*xs.w;
            acc[12] += vw.w*xs.x; acc[13] += vw.w*xs.y; acc[14] += vw.w*xs.z; acc[15] += vw.w*xs.w;
        }
#pragma unroll
        for (int a = 0; a < 4; ++a)
            *reinterpret_cast<float4*>(&M[(c * DD + dg * 4 + a) * NN + q * SLW + ng * 4]) =
                make_float4(acc[a*4], acc[a*4+1], acc[a*4+2], acc[a*4+3]);
    } else {
        // G[t][s] = sum_n Xs[t][n]*Xs[s][n] : 4t x 4s per thread
        const int tg = tid >> 4, sg = tid & 15;
        float acc[16];
#pragma unroll
        for (int k = 0; k < 16; ++k) acc[k] = 0.f;
        for (int n4 = 0; n4 < 16; ++n4) {
            float4 xa[4], xb[4];
#pragma unroll
            for (int a = 0; a < 4; ++a) xa[a] = Xs4[swz4(tg * 4 + a, n4)];
#pragma unroll
            for (int e = 0; e < 4; ++e) xb[e] = Xs4[swz4(sg * 4 + e, n4)];
#pragma unroll
            for (int a = 0; a < 4; ++a)
#pragma unroll
                for (int e = 0; e < 4; ++e) acc[a*4+e] += DOT4(xa[a], xb[e]);
        }
        float* base = Gp + ((size_t)(c * NSL + q) * CC) * CC;
#pragma unroll
        for (int a = 0; a < 4; ++a)
            *reinterpret_cast<float4*>(base + (tg * 4 + a) * CC + sg * 4) =
                make_float4(acc[a*4], acc[a*4+1], acc[a*4+2], acc[a*4+3]);
    }
}

// ---------------------------------------------------------------------------
// K4: segmented chunk scan of rho, fully float4. 512 blocks.
//     block covers 32 float4 columns; 8 segs x 4 chunks.
__global__ __launch_bounds__(NTHR) void k_rho(
    const float* __restrict__ M, const float* __restrict__ rho0, float* __restrict__ Rho)
{
    __shared__ float4 ssl[8][32];
    const int b = blockIdx.x, tid = threadIdx.x;
    const int l = tid & 31, seg = tid >> 5;              // 8 segs x 4 chunks
    const int f = b * 32 + l;                            // float4 col, 0..16383
    const float uc  = powf(UDEC, (float)CC);
    const float uc4 = uc * uc * uc * uc;
    const float4* M4 = reinterpret_cast<const float4*>(M);
    float4 mreg[4];
#pragma unroll
    for (int j = 0; j < 4; ++j) mreg[j] = M4[(size_t)(seg * 4 + j) * (DD * NN / 4) + f];
    float4 ss = mreg[0];
#pragma unroll
    for (int j = 1; j < 4; ++j) {
        ss.x = fmaf(ss.x, uc, mreg[j].x); ss.y = fmaf(ss.y, uc, mreg[j].y);
        ss.z = fmaf(ss.z, uc, mreg[j].z); ss.w = fmaf(ss.w, uc, mreg[j].w);
    }
    ssl[seg][l] = ss;
    __syncthreads();
    float4 acc = reinterpret_cast<const float4*>(rho0)[f];
    for (int r = 0; r < seg; ++r) {
        float4 sv = ssl[r][l];
        acc.x = fmaf(acc.x, uc4, sv.x); acc.y = fmaf(acc.y, uc4, sv.y);
        acc.z = fmaf(acc.z, uc4, sv.z); acc.w = fmaf(acc.w, uc4, sv.w);
    }
    float4* R4 = reinterpret_cast<float4*>(Rho);
#pragma unroll
    for (int j = 0; j < 4; ++j) {
        R4[(size_t)(seg * 4 + j) * (DD * NN / 4) + f] = acc;
        acc.x = fmaf(acc.x, uc, mreg[j].x); acc.y = fmaf(acc.y, uc, mreg[j].y);
        acc.z = fmaf(acc.z, uc, mreg[j].z); acc.w = fmaf(acc.w, uc, mreg[j].w);
    }
}

// ---------------------------------------------------------------------------
// K5: Pp[t][d] = sum_n X[t][n]*Rho[d][n], per (chunk, slice, t-half). 1024 blocks.
__global__ __launch_bounds__(NTHR) void k_inter(
    const float* __restrict__ Xp, const float* __restrict__ Bb,
    const float* __restrict__ Rho, float* __restrict__ Pp)
{
    __shared__ float Xs[32 * DD];
    __shared__ float Rs[DD * DD];
    const int b = blockIdx.x, tid = threadIdx.x;
    const int c = b >> 5, q = (b >> 1) & 15, h = b & 1;
    for (int i = tid; i < 32 * SLW / 4; i += NTHR) {     // float4 staging, 2 iters
        int s = i >> 4, n4 = i & 15;
        int t = c * CC + h * 32 + s;
        float4 xv = *reinterpret_cast<const float4*>(&Xp[t * NN + q * SLW + n4 * 4]);
        float4 bv = *reinterpret_cast<const float4*>(&Bb[(t >> 3) * NN + q * SLW + n4 * 4]);
        reinterpret_cast<float4*>(Xs)[swz4(s, n4)] = F4ADD(xv, bv);
    }
    for (int i = tid; i < DD * SLW / 4; i += NTHR) {     // float4 staging, 4 iters
        int s = i >> 4, n4 = i & 15;
        reinterpret_cast<float4*>(Rs)[swz4(s, n4)] =
            *reinterpret_cast<const float4*>(&Rho[(size_t)(c * DD + s) * NN + q * SLW + n4 * 4]);
    }
    __syncthreads();
    const float4* Xs4 = reinterpret_cast<const float4*>(Xs);
    const float4* Rs4 = reinterpret_cast<const float4*>(Rs);
    const int ti = tid >> 4, dg = tid & 15;              // 2 t x 4 d per thread
    float acc[8];
#pragma unroll
    for (int k = 0; k < 8; ++k) acc[k] = 0.f;
    for (int n4 = 0; n4 < 16; ++n4) {
        float4 xa[2], rv[4];
#pragma unroll
        for (int a = 0; a < 2; ++a) xa[a] = Xs4[swz4(ti * 2 + a, n4)];
#pragma unroll
        for (int e = 0; e < 4; ++e) rv[e] = Rs4[swz4(dg * 4 + e, n4)];
#pragma unroll
        for (int a = 0; a < 2; ++a)
#pragma unroll
            for (int e = 0; e < 4; ++e) acc[a*4+e] += DOT4(xa[a], rv[e]);
    }
#pragma unroll
    for (int a = 0; a < 2; ++a) {
        int trow = h * 32 + ti * 2 + a;
        *reinterpret_cast<float4*>(
            Pp + (((size_t)(c * NSL + q) * CC) + trow) * DD + dg * 4) =
            make_float4(acc[a*4], acc[a*4+1], acc[a*4+2], acc[a*4+3]);
    }
}

// ---------------------------------------------------------------------------
// K6: a* assembly + LN only. 512 blocks.
__global__ __launch_bounds__(NTHR) void k_astar(
    const float* __restrict__ Gp, const float* __restrict__ Pp,
    const float* __restrict__ temb, const int* __restrict__ toks,
    float* __restrict__ LNA)
{
    __shared__ float Ve[CC * DD];        // 16 KB
    __shared__ float Gt[4][CC];
    __shared__ float Pt[4][DD];
    __shared__ float pw[CC + 1];
    const int b = blockIdx.x, tid = threadIdx.x;
    const int c = b >> 4, sub = b & 15;                  // tokens t = sub + 16k, k<4
    if (tid <= CC) pw[tid] = powf(UDEC, (float)tid);
    for (int i = tid; i < CC * DD / 4; i += NTHR) {      // float4 staging
        int s = i >> 4, d4 = i & 15;
        reinterpret_cast<float4*>(Ve)[s * 16 + d4] =
            reinterpret_cast<const float4*>(temb + toks[c * CC + s] * DD)[d4];
    }
    {
        int k = tid >> 6, s = tid & 63;
        int t = sub + 16 * k;
        float ag = 0.f, ap = 0.f;
#pragma unroll
        for (int q = 0; q < NSL; ++q) {
            ag += Gp[((size_t)(c * NSL + q) * CC + t) * CC + s];
            ap += Pp[((size_t)(c * NSL + q) * CC + t) * DD + s];
        }
        Gt[k][s] = ag; Pt[k][s] = ap;
    }
    __syncthreads();
    {   // a* + LN, one wave per t-row
        const int tk = tid >> 6, d0 = tid & 63;
        const int t = sub + 16 * tk;
        float a = pw[t] * Pt[tk][d0];
        for (int s = 0; s < t; ++s)
            a = fmaf(pw[t - s] * Gt[tk][s], Ve[s * 64 + d0], a);
        float sum = a;
#pragma unroll
        for (int mm = 1; mm < 64; mm <<= 1) sum += __shfl_xor(sum, mm, 64);
        float mean = sum * (1.f / DD);
        float z = a - mean;
        float vv = z * z;
#pragma unroll
        for (int mm = 1; mm < 64; mm <<= 1) vv += __shfl_xor(vv, mm, 64);
        float inv = 1.f / (sqrtf(vv * (1.f / (DD - 1))) + EPS);
        LNA[(c * CC + t) * DD + d0] = z * inv;
    }
}

// ---------------------------------------------------------------------------
// K7: y[t][n] = relu(dot(LNA[t], Dy[n])) * relu(x[t][n]). grid (4, 256) = 1024.
__global__ __launch_bounds__(NTHR) void k_y(
    const float* __restrict__ LNA, const float* __restrict__ Dy,
    const float* __restrict__ Xp, const float* __restrict__ Bb,
    float* __restrict__ ys)
{
    __shared__ float L[8][DD];
    const int tt = blockIdx.y;                       // 8-token tile
    const int n  = blockIdx.x * 256 + threadIdx.x;
    for (int i = threadIdx.x; i < 8 * DD / 4; i += NTHR)     // float4 staging
        reinterpret_cast<float4*>(&L[0][0])[i] =
            reinterpret_cast<const float4*>(LNA + tt * 8 * DD)[i];
    __syncthreads();
    float dyr[DD];
    const float4* dy4 = reinterpret_cast<const float4*>(Dy + n * DD);
#pragma unroll
    for (int j = 0; j < 16; ++j) {
        float4 v = dy4[j];
        dyr[4*j] = v.x; dyr[4*j+1] = v.y; dyr[4*j+2] = v.z; dyr[4*j+3] = v.w;
    }
#pragma unroll
    for (int t = 0; t < 8; ++t) {
        const float4* lr = reinterpret_cast<const float4*>(&L[t][0]);
        float a0 = 0.f, a1 = 0.f, a2 = 0.f, a3 = 0.f;
#pragma unroll
        for (int j = 0; j < 16; ++j) {
            float4 v = lr[j];
            a0 += v.x * dyr[4*j];   a1 += v.y * dyr[4*j+1];
            a2 += v.z * dyr[4*j+2]; a3 += v.w * dyr[4*j+3];
        }
        float yc = (a0 + a1) + (a2 + a3);
        int tg = tt * 8 + t;
        float xv = Xp[tg * NN + n] + Bb[(tg >> 3) * NN + n];
        ys[tg * NN + n] = fmaxf(yc, 0.f) * fmaxf(xv, 0.f);
    }
}

// ---------------------------------------------------------------------------
// K8: vs[t] = LN(E @ y[t]) via transposed Et4, split-K across waves. 512 blocks.
__global__ __launch_bounds__(NTHR) void k_v(
    const float* __restrict__ ys, const float* __restrict__ Et4, float* __restrict__ vs)
{
    __shared__ float Ys[4][NN];          // 16 KB
    __shared__ float pre4[4][4][DD];     // [wave][token][d], 4 KB
    __shared__ float pre[4][DD + 1];
    __shared__ float mrow[4], srow[4];
    const int tt = blockIdx.x, tid = threadIdx.x;
    for (int i = tid; i < NN; i += NTHR)                 // float4 staging, 4 iters
        reinterpret_cast<float4*>(&Ys[0][0])[i] =
            reinterpret_cast<const float4*>(ys + (size_t)tt * 4 * NN)[i];
    __syncthreads();
    const int w = tid >> 6, d = tid & 63;
    float a0 = 0.f, a1 = 0.f, a2 = 0.f, a3 = 0.f;
    const float4* et = reinterpret_cast<const float4*>(Et4) + (size_t)w * 64 * DD + d;
#pragma unroll 4
    for (int i = 0; i < 64; ++i) {
        float4 ev = et[(size_t)i * DD];              // coalesced: lanes d consecutive
        const int n4g = (w * 64 + i) * 4;
        float4 y0 = *reinterpret_cast<const float4*>(&Ys[0][n4g]);   // broadcast
        float4 y1 = *reinterpret_cast<const float4*>(&Ys[1][n4g]);
        float4 y2 = *reinterpret_cast<const float4*>(&Ys[2][n4g]);
        float4 y3 = *reinterpret_cast<const float4*>(&Ys[3][n4g]);
        a0 += DOT4(ev, y0); a1 += DOT4(ev, y1);
        a2 += DOT4(ev, y2); a3 += DOT4(ev, y3);
    }
    pre4[w][0][d] = a0; pre4[w][1][d] = a1;
    pre4[w][2][d] = a2; pre4[w][3][d] = a3;
    __syncthreads();
    {
        const int k = tid >> 6, dd = tid & 63;
        pre[k][dd] = pre4[0][k][dd] + pre4[1][k][dd] + pre4[2][k][dd] + pre4[3][k][dd];
    }
    __syncthreads();
    if (tid < 4) {
        float m = 0.f;
#pragma unroll
        for (int dd2 = 0; dd2 < DD; ++dd2) m += pre[tid][dd2];
        m *= (1.f / DD);
        float v = 0.f;
#pragma unroll
        for (int dd2 = 0; dd2 < DD; ++dd2) { float z = pre[tid][dd2] - m; v += z * z; }
        mrow[tid] = m;
        srow[tid] = 1.f / (sqrtf(v * (1.f / (DD - 1))) + EPS);
    }
    __syncthreads();
    {
        int k = tid >> 6, dd = tid & 63;
        vs[(tt * 4 + k) * DD + dd] = (pre[k][dd] - mrow[k]) * srow[k];
    }
}

// ---------------------------------------------------------------------------
extern "C" void kernel_launch(void* const* d_in, const int* in_sizes, int n_in,
                              void* d_out, int out_size, void* d_ws, size_t ws_size,
                              hipStream_t stream) {
    (void)in_sizes; (void)n_in; (void)out_size; (void)ws_size;
    const float* E    = (const float*)d_in[0];   // [D,N]
    const float* Dx   = (const float*)d_in[1];   // [N,D]
    const float* Dy   = (const float*)d_in[2];   // [N,D]
    const float* temb = (const float*)d_in[3];   // [V,D]
    const float* x0   = (const float*)d_in[4];   // [N]
    const float* rho0 = (const float*)d_in[5];   // [D,N]
    const int*   toks = (const int*)d_in[6];     // [T]

    float* ys = (float*)d_out;                   // [T,N]
    float* vs = ys + (size_t)TT * NN;            // [T,D]

    // Workspace ~35 MiB. Pp aliases M (M dead after K4; Pp written in K5).
    float* w   = (float*)d_ws;
    float* Xp  = w;                                  // TT*NN         (8 MB)
    float* S   = Xp  + (size_t)TT * NN;              // NC2*NN        (1 MB)
    float* Bb  = S   + (size_t)NC2 * NN;             // NC2*NN        (1 MB)
    float* M   = Bb  + (size_t)NC2 * NN;             // NCH*DD*NN     (8 MB)
    float* Rho = M   + (size_t)NCH * DD * NN;        // NCH*DD*NN     (8 MB)
    float* Gp  = Rho + (size_t)NCH * DD * NN;        // NCH*NSL*CC*CC (8 MB)
    float* LNA = Gp  + (size_t)NCH * NSL * CC * CC;  // TT*DD         (0.5 MB)
    float* Et4 = LNA + (size_t)TT * DD;              // NN*DD         (0.25 MB)
    float* Pp  = M;                                  // alias

    k_xscan<<<dim3(4 * NC2),   NTHR, 0, stream>>>(Dx, temb, toks, Xp, S);
    k_base <<<dim3(96),        NTHR, 0, stream>>>(S, x0, Bb, E, Et4);
    k_mgram<<<dim3(NCH*NSL*2), NTHR, 0, stream>>>(Xp, Bb, temb, toks, M, Gp);
    k_rho  <<<dim3(512),       NTHR, 0, stream>>>(M, rho0, Rho);
    k_inter<<<dim3(NCH*NSL*2), NTHR, 0, stream>>>(Xp, Bb, Rho, Pp);
    k_astar<<<dim3(NCH*16),    NTHR, 0, stream>>>(Gp, Pp, temb, toks, LNA);
    k_y    <<<dim3(4, TT/8),   NTHR, 0, stream>>>(LNA, Dy, Xp, Bb, ys);
    k_v    <<<dim3(TT/4),      NTHR, 0, stream>>>(ys, Et4, vs);
}